// Round 6
// baseline (168.941 us; speedup 1.0000x reference)
//
#include <hip/hip_runtime.h>

#define CF 768
#define CCODE 70
#define NPIX 784
#define P 121
#define NB 32
#define NTOTF 468512.0f

#define OFF_PI_SCALAR 0
#define OFF_PI_CD 1
#define OFF_PO_SCALAR 468513
#define OFF_PO_CD 468514
#define OFF_NEG_LOSS 937026
#define OFF_NEG_CD 3279586

// ---- ws layout (floats) ----
#define WS_BSUMS 0             // 224*3
#define WS_ADDT 768            // 5
#define WS_NSQF 1024           // 8 slots * 32 n * 12 sub * 128 pt = 393216
#define WS_NSQC 394240         // 7 slots * 32 n * 3 sub * 128 pt = 86016
#define WS_FRAG_FLOAT 480256   // bf16 fragment region starts here
#define FEAT_FRAG_SHORTS 98304 // 24 panels * 8 tiles * 64 lanes * 8
#define CODE_FRAG_SHORTS 12288 // 3 panels * 8 * 64 * 8
#define FEATS_TOTAL_SHORTS (8 * 32 * FEAT_FRAG_SHORTS)
#define CODE_BASE_SHORTS FEATS_TOTAL_SHORTS
#define CODE_TOTAL_SHORTS (7 * 32 * CODE_FRAG_SHORTS)
#define WS_NEED2 (WS_FRAG_FLOAT + (FEATS_TOTAL_SHORTS + CODE_TOTAL_SHORTS) / 2)

typedef __attribute__((ext_vector_type(8))) short short8;
typedef __attribute__((ext_vector_type(4))) float f32x4;
typedef unsigned short ushort_t;
typedef unsigned int uint_t;

// 8-byte pair with 4-byte alignment (dwordx2-able, halves scattered loads)
struct __attribute__((packed, aligned(4))) f2u {
  float x, y;
};

__device__ __forceinline__ float samp4(const float* __restrict__ img, int c,
                                       const int4 o, const float4 w) {
  const float* p = img + c * NPIX;
  return w.x * p[o.x] + w.y * p[o.y] + w.z * p[o.z] + w.w * p[o.w];
}

__device__ __forceinline__ void mkcoord(const float* cp, int4* o, float4* w) {
  float x = fminf(fmaxf(cp[0] * 27.f, 0.f), 27.f);
  float y = fminf(fmaxf(cp[1] * 27.f, 0.f), 27.f);
  float x0f = floorf(x), y0f = floorf(y);
  int x0 = (int)x0f, y0 = (int)y0f;
  int x1 = min(x0 + 1, 27), y1 = min(y0 + 1, 27);
  float wx = x - x0f, wy = y - y0f;
  *o = make_int4(y0 * 28 + x0, y0 * 28 + x1, y1 * 28 + x0, y1 * 28 + x1);
  *w = make_float4((1.f - wx) * (1.f - wy), wx * (1.f - wy),
                   (1.f - wx) * wy, wx * wy);
}

// pair-based coords: o = (row0 base, row1 base), w = (wa0, wa1, wb0, wb1)
// value = wa0*p[o.x] + wa1*p[o.x+1] + wb0*p[o.y] + wb1*p[o.y+1]
__device__ __forceinline__ void mkcoord2(const float* cp, int2* o, float4* w) {
  float x = fminf(fmaxf(cp[0] * 27.f, 0.f), 27.f);
  float y = fminf(fmaxf(cp[1] * 27.f, 0.f), 27.f);
  float x0f = floorf(x), y0f = floorf(y);
  int x0 = (int)x0f, y0 = (int)y0f;
  int y1 = min(y0 + 1, 27);
  float wx = x - x0f, wy = y - y0f;
  bool sh = (x0 >= 27);
  int xb = sh ? 26 : x0;
  float wa0 = sh ? 0.f : (1.f - wx) * (1.f - wy);
  float wa1 = sh ? (1.f - wy) : wx * (1.f - wy);
  float wb0 = sh ? 0.f : (1.f - wx) * wy;
  float wb1 = sh ? wy : wx * wy;
  *o = make_int2(y0 * 28 + xb, y1 * 28 + xb);
  *w = make_float4(wa0, wa1, wb0, wb1);
}

__device__ __forceinline__ ushort_t f2bf(float x) {
  uint_t u = __float_as_uint(x);
  u += 0x7fffu + ((u >> 16) & 1u);
  return (ushort_t)(u >> 16);
}

// ===================== presample (fine-grained grid) =====================
// frag layout per (slot,n): ((kp*8 + tile)*64 + lane)*8 + i  (bf16)
// value = sample(channel = kp*32 + (lane>>4)*8 + i, point = tile*16 + (lane&15))
// feats jobs: slot(8) x n(32) x sub(12); each sub covers 8 octets (64 ch),
//   thread-half h takes octets sub*8 + 2k + h, k=0..3 (4 iters).
// code jobs: slot(7) x n(32) x sub(3); each sub covers 4 octets, 2 iters.
__global__ __launch_bounds__(256) void presample5(
    const float* __restrict__ OF, const float* __restrict__ OFP,
    const float* __restrict__ OC, const float* __restrict__ OCP,
    const float* __restrict__ DAF,
    const float* __restrict__ CO1, const float* __restrict__ CO2,
    const int* __restrict__ PERMS, float* __restrict__ ws) {
  ushort_t* frags = (ushort_t*)(ws + WS_FRAG_FLOAT);
  __shared__ float ssum[2][128];
  const int job = blockIdx.x, tid = threadIdx.x;
  const int pt = tid & 127, h = tid >> 7;
  const float* src;
  const float* cb;
  int slot, sub, n, octet0, niter, nch;
  size_t fragbase;
  float* nsqp;
  if (job < 3072) {
    slot = job / 384;
    int rem = job - slot * 384;
    n = rem / 12;
    sub = rem - n * 12;
    octet0 = sub * 8;
    niter = 4;
    nch = CF;
    int m = n;
    if (slot == 0) { src = DAF; cb = CO1; }
    else if (slot == 1) { src = OF; cb = CO1; }
    else if (slot == 2) { src = OFP; cb = CO2; }
    else { m = PERMS[(slot - 3) * NB + n]; src = OF; cb = CO2; }
    src += (size_t)m * CF * NPIX;
    fragbase = (size_t)(slot * 32 + n) * FEAT_FRAG_SHORTS;
    nsqp = ws + WS_NSQF + (size_t)((slot * 32 + n) * 12 + sub) * 128;
  } else {
    int q = job - 3072;
    slot = q / 96;
    int rem = q - slot * 96;
    n = rem / 3;
    sub = rem - n * 3;
    octet0 = sub * 4;
    niter = 2;
    nch = CCODE;
    int m = n;
    if (slot == 0) { src = OC; cb = CO1; }
    else if (slot == 1) { src = OCP; cb = CO2; }
    else { m = PERMS[(slot - 2) * NB + n]; src = OC; cb = CO2; }
    src += (size_t)m * CCODE * NPIX;
    fragbase = CODE_BASE_SHORTS + (size_t)(slot * 32 + n) * CODE_FRAG_SHORTS;
    nsqp = ws + WS_NSQC + (size_t)((slot * 32 + n) * 3 + sub) * 128;
  }

  // per-thread coords (both halves compute the same; tiny)
  int2 o2 = make_int2(0, 0);
  float4 w4 = make_float4(0.f, 0.f, 0.f, 0.f);
  if (pt < P) {
    int gi = pt / 11, gj = pt - gi * 11;
    mkcoord2(cb + (((n * 11 + gj) * 11 + gi) << 1), &o2, &w4);
  }
  const int tile = pt >> 4;
  float sumsq = 0.f;

  for (int k = 0; k < niter; ++k) {
    const int o = octet0 + 2 * k + h;
    const int c0 = o * 8;
    const float* base = src + (size_t)c0 * NPIX;
    float v[8];
    if (c0 + 7 < nch) {
      f2u pa[8], pb[8];
#pragma unroll
      for (int i = 0; i < 8; ++i) {
        const float* p = base + i * NPIX;
        pa[i] = *(const f2u*)(p + o2.x);
        pb[i] = *(const f2u*)(p + o2.y);
      }
#pragma unroll
      for (int i = 0; i < 8; ++i) {
        float x = w4.x * pa[i].x + w4.y * pa[i].y + w4.z * pb[i].x + w4.w * pb[i].y;
        v[i] = x;
        sumsq = fmaf(x, x, sumsq);
      }
    } else {
#pragma unroll
      for (int i = 0; i < 8; ++i) {
        float x = 0.f;
        if (c0 + i < nch) {
          const float* p = base + i * NPIX;
          f2u a = *(const f2u*)(p + o2.x);
          f2u b = *(const f2u*)(p + o2.y);
          x = w4.x * a.x + w4.y * a.y + w4.z * b.x + w4.w * b.y;
        }
        v[i] = x;
        sumsq = fmaf(x, x, sumsq);
      }
    }
    uint4 q;
    q.x = (uint_t)f2bf(v[0]) | ((uint_t)f2bf(v[1]) << 16);
    q.y = (uint_t)f2bf(v[2]) | ((uint_t)f2bf(v[3]) << 16);
    q.z = (uint_t)f2bf(v[4]) | ((uint_t)f2bf(v[5]) << 16);
    q.w = (uint_t)f2bf(v[6]) | ((uint_t)f2bf(v[7]) << 16);
    const int kp = o >> 2, lg = o & 3;
    const int lane = lg * 16 + (pt & 15);
    *(uint4*)(frags + fragbase + ((size_t)((kp * 8 + tile) * 64 + lane) << 3)) = q;
  }

  ssum[h][pt] = sumsq;
  __syncthreads();
  if (tid < 128) nsqp[tid] = ssum[0][tid] + ssum[1][tid];
}

// ===================== MFMA Gram =====================
__global__ __launch_bounds__(256) void gram_mfma(float* __restrict__ ws,
                                                 float* __restrict__ out) {
  const ushort_t* frags = (const ushort_t*)(ws + WS_FRAG_FLOAT);
  const int bid = blockIdx.x, pair = bid >> 5, n = bid & 31;
  const int tid = threadIdx.x, wave = tid >> 6, lane = tid & 63;
  __shared__ float invAf[128], invBf[128], invAc[128], invBc[128];
  __shared__ float red[4][3];
  const int afslot = (pair == 0) ? 0 : 1;
  const int bfslot = (pair == 0) ? 0 : (pair == 1 ? 2 : 3 + (pair - 2));
  const int bcslot = (pair == 0) ? 0 : (pair == 1 ? 1 : 2 + (pair - 2));
  if (tid < 128) {
    float s;
    const float* pf;
    pf = ws + WS_NSQF + (size_t)(afslot * 32 + n) * 12 * 128 + tid;
    s = 0.f;
#pragma unroll
    for (int u = 0; u < 12; ++u) s += pf[u * 128];
    invAf[tid] = 1.f / fmaxf(sqrtf(s), 1e-10f);
    pf = ws + WS_NSQF + (size_t)(bfslot * 32 + n) * 12 * 128 + tid;
    s = 0.f;
#pragma unroll
    for (int u = 0; u < 12; ++u) s += pf[u * 128];
    invBf[tid] = 1.f / fmaxf(sqrtf(s), 1e-10f);
    pf = ws + WS_NSQC + (size_t)(0 * 32 + n) * 3 * 128 + tid;
    s = pf[0] + pf[128] + pf[256];
    invAc[tid] = 1.f / fmaxf(sqrtf(s), 1e-10f);
    pf = ws + WS_NSQC + (size_t)(bcslot * 32 + n) * 3 * 128 + tid;
    s = pf[0] + pf[128] + pf[256];
    invBc[tid] = 1.f / fmaxf(sqrtf(s), 1e-10f);
  }
  __syncthreads();

  const short8* Af = (const short8*)(frags + (size_t)(afslot * 32 + n) * FEAT_FRAG_SHORTS);
  const short8* Bf = (const short8*)(frags + (size_t)(bfslot * 32 + n) * FEAT_FRAG_SHORTS);

  f32x4 acc[2][8];
#pragma unroll
  for (int j = 0; j < 2; ++j)
#pragma unroll
    for (int t = 0; t < 8; ++t) acc[j][t] = (f32x4){0.f, 0.f, 0.f, 0.f};

#pragma unroll 2
  for (int kp = 0; kp < 24; ++kp) {
    short8 a0 = Af[(kp * 8 + 2 * wave) * 64 + lane];
    short8 a1 = Af[(kp * 8 + 2 * wave + 1) * 64 + lane];
    short8 bv[8];
#pragma unroll
    for (int t = 0; t < 8; ++t) bv[t] = Bf[(kp * 8 + t) * 64 + lane];
#pragma unroll
    for (int t = 0; t < 8; ++t) {
      acc[0][t] = __builtin_amdgcn_mfma_f32_16x16x32_bf16(a0, bv[t], acc[0][t], 0, 0, 0);
      acc[1][t] = __builtin_amdgcn_mfma_f32_16x16x32_bf16(a1, bv[t], acc[1][t], 0, 0, 0);
    }
  }

  // ---- feats epilogue: normalize, row-center (fd kept in acc) ----
  const int lane4 = (lane >> 4) << 2;
  const int cl15 = lane & 15;
  float sfd = 0.f;
#pragma unroll
  for (int j = 0; j < 2; ++j) {
    const int rb = (2 * wave + j) * 16 + lane4;
    const float ivr0 = invAf[rb], ivr1 = invAf[rb + 1], ivr2 = invAf[rb + 2],
                ivr3 = invAf[rb + 3];
    float rs0 = 0.f, rs1 = 0.f, rs2 = 0.f, rs3 = 0.f;
#pragma unroll
    for (int t = 0; t < 8; ++t) {
      const float ivc = invBf[t * 16 + cl15];
      float v0 = acc[j][t].x * ivr0 * ivc;
      float v1 = acc[j][t].y * ivr1 * ivc;
      float v2 = acc[j][t].z * ivr2 * ivc;
      float v3 = acc[j][t].w * ivr3 * ivc;
      acc[j][t].x = v0; acc[j][t].y = v1; acc[j][t].z = v2; acc[j][t].w = v3;
      rs0 += v0; rs1 += v1; rs2 += v2; rs3 += v3;
    }
    sfd += rs0 + rs1 + rs2 + rs3;
    rs0 += __shfl_xor(rs0, 1); rs0 += __shfl_xor(rs0, 2);
    rs0 += __shfl_xor(rs0, 4); rs0 += __shfl_xor(rs0, 8);
    rs1 += __shfl_xor(rs1, 1); rs1 += __shfl_xor(rs1, 2);
    rs1 += __shfl_xor(rs1, 4); rs1 += __shfl_xor(rs1, 8);
    rs2 += __shfl_xor(rs2, 1); rs2 += __shfl_xor(rs2, 2);
    rs2 += __shfl_xor(rs2, 4); rs2 += __shfl_xor(rs2, 8);
    rs3 += __shfl_xor(rs3, 1); rs3 += __shfl_xor(rs3, 2);
    rs3 += __shfl_xor(rs3, 4); rs3 += __shfl_xor(rs3, 8);
    const float rm0 = rs0 * (1.f / 121.f), rm1 = rs1 * (1.f / 121.f);
    const float rm2 = rs2 * (1.f / 121.f), rm3 = rs3 * (1.f / 121.f);
#pragma unroll
    for (int t = 0; t < 8; ++t) {
      acc[j][t].x -= rm0; acc[j][t].y -= rm1; acc[j][t].z -= rm2; acc[j][t].w -= rm3;
    }
  }

  int cd_base, loss_base = 0;
  if (pair == 0) cd_base = OFF_PI_CD + n * 14641;
  else if (pair == 1) cd_base = OFF_PO_CD + n * 14641;
  else {
    int t0 = ((pair - 2) * NB + n) * 14641;
    cd_base = OFF_NEG_CD + t0;
    loss_base = OFF_NEG_LOSS + t0;
  }

  if (pair >= 2) {
#pragma unroll
    for (int j = 0; j < 2; ++j) {
      const int rb = (2 * wave + j) * 16 + lane4;
      if (rb < P) {
#pragma unroll
        for (int t = 0; t < 8; ++t) {
          const int c = t * 16 + cl15;
          if (c < P) {
            float* o = out + loss_base + rb * P + c;
            o[0] = acc[j][t].x;
            if (rb + 1 < P) o[P] = acc[j][t].y;
            if (rb + 2 < P) o[2 * P] = acc[j][t].z;
            if (rb + 3 < P) o[3 * P] = acc[j][t].w;
          }
        }
      }
    }
  }

  // ---- code Gram ----
  const short8* Ac = (const short8*)(frags + CODE_BASE_SHORTS + (size_t)n * CODE_FRAG_SHORTS);
  const short8* Bc = (const short8*)(frags + CODE_BASE_SHORTS + (size_t)(bcslot * 32 + n) * CODE_FRAG_SHORTS);
  f32x4 cacc[2][8];
#pragma unroll
  for (int j = 0; j < 2; ++j)
#pragma unroll
    for (int t = 0; t < 8; ++t) cacc[j][t] = (f32x4){0.f, 0.f, 0.f, 0.f};
#pragma unroll
  for (int kp = 0; kp < 3; ++kp) {
    short8 a0 = Ac[(kp * 8 + 2 * wave) * 64 + lane];
    short8 a1 = Ac[(kp * 8 + 2 * wave + 1) * 64 + lane];
    short8 bv[8];
#pragma unroll
    for (int t = 0; t < 8; ++t) bv[t] = Bc[(kp * 8 + t) * 64 + lane];
#pragma unroll
    for (int t = 0; t < 8; ++t) {
      cacc[0][t] = __builtin_amdgcn_mfma_f32_16x16x32_bf16(a0, bv[t], cacc[0][t], 0, 0, 0);
      cacc[1][t] = __builtin_amdgcn_mfma_f32_16x16x32_bf16(a1, bv[t], cacc[1][t], 0, 0, 0);
    }
  }

  float s1 = 0.f, s2 = 0.f;
#pragma unroll
  for (int j = 0; j < 2; ++j) {
    const int rb = (2 * wave + j) * 16 + lane4;
    const float ivr0 = invAc[rb], ivr1 = invAc[rb + 1], ivr2 = invAc[rb + 2],
                ivr3 = invAc[rb + 3];
#pragma unroll
    for (int t = 0; t < 8; ++t) {
      const int c = t * 16 + cl15;
      const float ivc = invBc[c];
      float c0v = cacc[j][t].x * ivr0 * ivc;
      float c1v = cacc[j][t].y * ivr1 * ivc;
      float c2v = cacc[j][t].z * ivr2 * ivc;
      float c3v = cacc[j][t].w * ivr3 * ivc;
      if (c < P && rb < P) {
        float* o = out + cd_base + rb * P + c;
        o[0] = c0v;
        if (rb + 1 < P) o[P] = c1v;
        if (rb + 2 < P) o[2 * P] = c2v;
        if (rb + 3 < P) o[3 * P] = c3v;
      }
      if (pair < 2) {
        float cl0 = fminf(fmaxf(c0v, 0.f), 0.8f);
        float cl1 = fminf(fmaxf(c1v, 0.f), 0.8f);
        float cl2 = fminf(fmaxf(c2v, 0.f), 0.8f);
        float cl3 = fminf(fmaxf(c3v, 0.f), 0.8f);
        s1 = fmaf(cl0, acc[j][t].x, s1);
        s1 = fmaf(cl1, acc[j][t].y, s1);
        s1 = fmaf(cl2, acc[j][t].z, s1);
        s1 = fmaf(cl3, acc[j][t].w, s1);
        s2 += cl0 + cl1 + cl2 + cl3;
      }
    }
  }

#pragma unroll
  for (int m = 1; m < 64; m <<= 1) {
    sfd += __shfl_xor(sfd, m);
    s1 += __shfl_xor(s1, m);
    s2 += __shfl_xor(s2, m);
  }
  if ((tid & 63) == 0) { red[wave][0] = sfd; red[wave][1] = s1; red[wave][2] = s2; }
  __syncthreads();
  if (tid == 0) {
    float a = 0.f, b2 = 0.f, c2 = 0.f;
    for (int w = 0; w < 4; ++w) { a += red[w][0]; b2 += red[w][1]; c2 += red[w][2]; }
    float* bsums = ws + WS_BSUMS;
    bsums[bid * 3 + 0] = a;
    bsums[bid * 3 + 1] = b2;
    bsums[bid * 3 + 2] = c2;
  }
}

__global__ void loss_finish2(float* __restrict__ ws, float* __restrict__ out) {
  __shared__ float s[7][3];
  const float* bsums = ws + WS_BSUMS;
  float* addterm = ws + WS_ADDT;
  int tid = threadIdx.x;
  if (tid < 21) {
    int pr = tid / 3, k = tid % 3;
    float a = 0.f;
    for (int i = 0; i < 32; ++i) a += bsums[(pr * 32 + i) * 3 + k];
    s[pr][k] = a;
  }
  __syncthreads();
  if (tid == 0) {
    const float invN = 1.f / NTOTF;
    out[OFF_PI_SCALAR] = -(s[0][1] + (s[0][0] * invN - 0.18f) * s[0][2]) * invN;
    out[OFF_PO_SCALAR] = -(s[1][1] + (s[1][0] * invN - 0.12f) * s[1][2]) * invN;
  }
  if (tid >= 1 && tid < 6) addterm[tid - 1] = s[tid + 1][0] / NTOTF - 0.46f;
}

__global__ __launch_bounds__(256) void neg_loss_kernel(
    float* __restrict__ lossr, const float* __restrict__ cdr,
    const float* __restrict__ addterm) {
  __shared__ float at[5];
  if (threadIdx.x < 5) at[threadIdx.x] = addterm[threadIdx.x];
  __syncthreads();
  const int total4 = 5 * 117128;  // 468512/4 per pair
  float4* l4 = (float4*)lossr;
  const float4* c4 = (const float4*)cdr;
  for (int e = blockIdx.x * 256 + threadIdx.x; e < total4; e += gridDim.x * 256) {
    int k = e / 117128;
    float4 cd = c4[e];
    float4 fv = l4[e];
    float a = at[k];
    float4 r;
    r.x = -fminf(fmaxf(cd.x, 0.f), 0.8f) * (fv.x + a);
    r.y = -fminf(fmaxf(cd.y, 0.f), 0.8f) * (fv.y + a);
    r.z = -fminf(fmaxf(cd.z, 0.f), 0.8f) * (fv.z + a);
    r.w = -fminf(fmaxf(cd.w, 0.f), 0.8f) * (fv.w + a);
    l4[e] = r;
  }
}

// ===================== fallback path (round-1, verified) =====================

__global__ __launch_bounds__(256) void loss_main_fb(
    const float* __restrict__ OF, const float* __restrict__ OFP,
    const float* __restrict__ OC, const float* __restrict__ OCP,
    const float* __restrict__ DAF,
    const float* __restrict__ CO1, const float* __restrict__ CO2,
    const int* __restrict__ PERMS,
    float* __restrict__ out, float* __restrict__ bsums) {
  const int b = blockIdx.x;
  const int pair = b >> 7;
  const int rem = b & 127;
  const int n = rem >> 2;
  const int rg = rem & 3;
  const int row_start = rg * 31;
  const int rcount = min(31, P - row_start);
  const int tid = threadIdx.x;
  const int tx = tid & 15, ty = tid >> 4;

  const float *F1, *F2, *C1, *C2, *CB;
  if (pair == 0) {
    F1 = DAF + (size_t)n * CF * NPIX; F2 = F1;
    C1 = OC + (size_t)n * CCODE * NPIX; C2 = C1;
    CB = CO1;
  } else if (pair == 1) {
    F1 = OF + (size_t)n * CF * NPIX; F2 = OFP + (size_t)n * CF * NPIX;
    C1 = OC + (size_t)n * CCODE * NPIX; C2 = OCP + (size_t)n * CCODE * NPIX;
    CB = CO2;
  } else {
    int n2 = PERMS[(pair - 2) * NB + n];
    F1 = OF + (size_t)n * CF * NPIX; F2 = OF + (size_t)n2 * CF * NPIX;
    C1 = OC + (size_t)n * CCODE * NPIX; C2 = OC + (size_t)n2 * CCODE * NPIX;
    CB = CO2;
  }

  __shared__ int4 Bo[P];
  __shared__ float4 Bw[P];
  __shared__ int4 Ao[32];
  __shared__ float4 Aw[32];
  __shared__ float Abuf[CCODE][32];
  __shared__ float Bbuf[CCODE][128];
  __shared__ float invA[32], invB[128];
  __shared__ float red[4][3];

  if (tid < P) {
    int gi = tid / 11, gj = tid - gi * 11;
    const float* cp = CB + (((n * 11 + gj) * 11 + gi) << 1);
    mkcoord(cp, &Bo[tid], &Bw[tid]);
  } else if (tid >= 128 && tid < 160) {
    int r = tid - 128;
    int q = row_start + r;
    if (q < P) {
      int gi = q / 11, gj = q - gi * 11;
      const float* cp = CO1 + (((n * 11 + gj) * 11 + gi) << 1);
      mkcoord(cp, &Ao[r], &Aw[r]);
    }
  }
  __syncthreads();

  float acc[2][2][4];
#pragma unroll
  for (int kr = 0; kr < 2; ++kr)
#pragma unroll
    for (int m = 0; m < 2; ++m)
#pragma unroll
      for (int u = 0; u < 4; ++u) acc[kr][m][u] = 0.f;
  float ansq = 0.f, bnsq = 0.f;

  for (int ch = 0; ch < 12; ++ch) {
    const int c0 = ch * 64;
    if (ch) __syncthreads();
    for (int e = tid; e < 64 * 128; e += 256) {
      int col = e & 127, cc = e >> 7;
      float v = 0.f;
      if (col < P) v = samp4(F2, c0 + cc, Bo[col], Bw[col]);
      Bbuf[cc][col] = v;
    }
    for (int e = tid; e < 64 * 32; e += 256) {
      int col = e & 31, cc = e >> 5;
      float v = 0.f;
      if (col < rcount) v = samp4(F1, c0 + cc, Ao[col], Aw[col]);
      Abuf[cc][col] = v;
    }
    __syncthreads();
    if (tid < 128) {
      float s = 0.f;
      for (int cc = 0; cc < 64; ++cc) { float v = Bbuf[cc][tid]; s = fmaf(v, v, s); }
      bnsq += s;
    } else if (tid < 160) {
      int r = tid - 128;
      float s = 0.f;
      for (int cc = 0; cc < 64; ++cc) { float v = Abuf[cc][r]; s = fmaf(v, v, s); }
      ansq += s;
    }
    for (int cc = 0; cc < 64; ++cc) {
      const float2 av = *(const float2*)&Abuf[cc][ty * 2];
      const float4 b0 = *(const float4*)&Bbuf[cc][tx * 4];
      const float4 b1 = *(const float4*)&Bbuf[cc][tx * 4 + 64];
      float a[2] = {av.x, av.y};
      float bb[2][4] = {{b0.x, b0.y, b0.z, b0.w}, {b1.x, b1.y, b1.z, b1.w}};
#pragma unroll
      for (int kr = 0; kr < 2; ++kr)
#pragma unroll
        for (int m = 0; m < 2; ++m)
#pragma unroll
          for (int u = 0; u < 4; ++u)
            acc[kr][m][u] = fmaf(a[kr], bb[m][u], acc[kr][m][u]);
    }
  }
  __syncthreads();
  if (tid < 128) invB[tid] = (tid < P) ? 1.f / fmaxf(sqrtf(bnsq), 1e-10f) : 0.f;
  else if (tid < 160) {
    int r = tid - 128;
    invA[r] = (r < rcount) ? 1.f / fmaxf(sqrtf(ansq), 1e-10f) : 0.f;
  }
  __syncthreads();

  float ia[2] = {invA[2 * ty], invA[2 * ty + 1]};
  float ib[2][4];
#pragma unroll
  for (int m = 0; m < 2; ++m)
#pragma unroll
    for (int u = 0; u < 4; ++u) ib[m][u] = invB[m * 64 + tx * 4 + u];

  float fdc[2][2][4];
  float sfd = 0.f;
#pragma unroll
  for (int kr = 0; kr < 2; ++kr) {
    float part = 0.f;
#pragma unroll
    for (int m = 0; m < 2; ++m)
#pragma unroll
      for (int u = 0; u < 4; ++u) {
        float v = acc[kr][m][u] * ia[kr] * ib[m][u];
        fdc[kr][m][u] = v;
        part += v;
      }
    sfd += part;
    float rs = part;
#pragma unroll
    for (int s = 1; s < 16; s <<= 1) rs += __shfl_xor(rs, s, 16);
    float rowm = rs * (1.f / 121.f);
#pragma unroll
    for (int m = 0; m < 2; ++m)
#pragma unroll
      for (int u = 0; u < 4; ++u) fdc[kr][m][u] -= rowm;
  }
  __syncthreads();

  for (int e = tid; e < CCODE * 128; e += 256) {
    int col = e & 127, cc = e >> 7;
    float v = 0.f;
    if (col < P) v = samp4(C2, cc, Bo[col], Bw[col]);
    Bbuf[cc][col] = v;
  }
  for (int e = tid; e < CCODE * 32; e += 256) {
    int col = e & 31, cc = e >> 5;
    float v = 0.f;
    if (col < rcount) v = samp4(C1, cc, Ao[col], Aw[col]);
    Abuf[cc][col] = v;
  }
  __syncthreads();
  if (tid < 128) {
    float s = 0.f;
    for (int cc = 0; cc < CCODE; ++cc) { float v = Bbuf[cc][tid]; s = fmaf(v, v, s); }
    invB[tid] = (tid < P) ? 1.f / fmaxf(sqrtf(s), 1e-10f) : 0.f;
  } else if (tid < 160) {
    int r = tid - 128;
    float s = 0.f;
    for (int cc = 0; cc < CCODE; ++cc) { float v = Abuf[cc][r]; s = fmaf(v, v, s); }
    invA[r] = (r < rcount) ? 1.f / fmaxf(sqrtf(s), 1e-10f) : 0.f;
  }
  float cacc[2][2][4];
#pragma unroll
  for (int kr = 0; kr < 2; ++kr)
#pragma unroll
    for (int m = 0; m < 2; ++m)
#pragma unroll
      for (int u = 0; u < 4; ++u) cacc[kr][m][u] = 0.f;
  for (int cc = 0; cc < CCODE; ++cc) {
    const float2 av = *(const float2*)&Abuf[cc][ty * 2];
    const float4 b0 = *(const float4*)&Bbuf[cc][tx * 4];
    const float4 b1 = *(const float4*)&Bbuf[cc][tx * 4 + 64];
    float a[2] = {av.x, av.y};
    float bb[2][4] = {{b0.x, b0.y, b0.z, b0.w}, {b1.x, b1.y, b1.z, b1.w}};
#pragma unroll
    for (int kr = 0; kr < 2; ++kr)
#pragma unroll
      for (int m = 0; m < 2; ++m)
#pragma unroll
        for (int u = 0; u < 4; ++u)
          cacc[kr][m][u] = fmaf(a[kr], bb[m][u], cacc[kr][m][u]);
  }
  __syncthreads();
  float iac[2] = {invA[2 * ty], invA[2 * ty + 1]};
  float ibc[2][4];
#pragma unroll
  for (int m = 0; m < 2; ++m)
#pragma unroll
    for (int u = 0; u < 4; ++u) ibc[m][u] = invB[m * 64 + tx * 4 + u];

  int cd_base, loss_base = 0;
  if (pair == 0) cd_base = OFF_PI_CD + n * 14641;
  else if (pair == 1) cd_base = OFF_PO_CD + n * 14641;
  else {
    int t = ((pair - 2) * NB + n) * 14641;
    cd_base = OFF_NEG_CD + t;
    loss_base = OFF_NEG_LOSS + t;
  }

  float s1 = 0.f, s2 = 0.f;
#pragma unroll
  for (int kr = 0; kr < 2; ++kr) {
    int r = 2 * ty + kr;
    if (r < rcount) {
      int rglob = row_start + r;
#pragma unroll
      for (int m = 0; m < 2; ++m)
#pragma unroll
        for (int u = 0; u < 4; ++u) {
          int c = m * 64 + tx * 4 + u;
          if (c < P) {
            float cdv = cacc[kr][m][u] * iac[kr] * ibc[m][u];
            int idx = rglob * P + c;
            out[cd_base + idx] = cdv;
            float cl = fminf(fmaxf(cdv, 0.f), 0.8f);
            float fv = fdc[kr][m][u];
            if (pair < 2) { s1 = fmaf(cl, fv, s1); s2 += cl; }
            else out[loss_base + idx] = fv;
          }
        }
    }
  }

#pragma unroll
  for (int s = 1; s < 64; s <<= 1) {
    sfd += __shfl_xor(sfd, s);
    s1 += __shfl_xor(s1, s);
    s2 += __shfl_xor(s2, s);
  }
  int wv = tid >> 6;
  if ((tid & 63) == 0) { red[wv][0] = sfd; red[wv][1] = s1; red[wv][2] = s2; }
  __syncthreads();
  if (tid == 0) {
    float a = 0.f, bb = 0.f, cc = 0.f;
    for (int w = 0; w < 4; ++w) { a += red[w][0]; bb += red[w][1]; cc += red[w][2]; }
    bsums[b * 3 + 0] = a;
    bsums[b * 3 + 1] = bb;
    bsums[b * 3 + 2] = cc;
  }
}

__global__ void loss_finish_fb(const float* __restrict__ bsums,
                               float* __restrict__ out,
                               float* __restrict__ addterm) {
  __shared__ float s[7][3];
  int tid = threadIdx.x;
  if (tid < 21) {
    int pr = tid / 3, k = tid % 3;
    float a = 0.f;
    const float* p = bsums + (pr * 128) * 3 + k;
    for (int i = 0; i < 128; ++i) a += p[i * 3];
    s[pr][k] = a;
  }
  __syncthreads();
  if (tid == 0) {
    const float invN = 1.f / NTOTF;
    out[OFF_PI_SCALAR] = -(s[0][1] + (s[0][0] * invN - 0.18f) * s[0][2]) * invN;
    out[OFF_PO_SCALAR] = -(s[1][1] + (s[1][0] * invN - 0.12f) * s[1][2]) * invN;
  }
  if (tid >= 1 && tid < 6) addterm[tid - 1] = s[tid + 1][0] / NTOTF - 0.46f;
}

__global__ __launch_bounds__(256) void neg_loss_fb(
    float* __restrict__ lossr, const float* __restrict__ cdr,
    const float* __restrict__ addterm) {
  __shared__ float at[5];
  if (threadIdx.x < 5) at[threadIdx.x] = addterm[threadIdx.x];
  __syncthreads();
  const int total = 5 * 468512;
  for (int e = blockIdx.x * 256 + threadIdx.x; e < total; e += gridDim.x * 256) {
    int k = e / 468512;
    float cdv = cdr[e];
    float cl = fminf(fmaxf(cdv, 0.f), 0.8f);
    lossr[e] = -cl * (lossr[e] + at[k]);
  }
}

extern "C" void kernel_launch(void* const* d_in, const int* in_sizes, int n_in,
                              void* d_out, int out_size, void* d_ws,
                              size_t ws_size, hipStream_t stream) {
  const float* OF = (const float*)d_in[0];
  const float* OFP = (const float*)d_in[1];
  const float* OC = (const float*)d_in[4];
  const float* OCP = (const float*)d_in[5];
  const float* DAF = (const float*)d_in[6];
  const float* CO1 = (const float*)d_in[8];
  const float* CO2 = (const float*)d_in[9];
  const int* PERMS = (const int*)d_in[10];
  float* out = (float*)d_out;
  float* ws = (float*)d_ws;

  if (ws_size >= (size_t)WS_NEED2 * sizeof(float)) {
    hipLaunchKernelGGL(presample5, dim3(3744), dim3(256), 0, stream,
                       OF, OFP, OC, OCP, DAF, CO1, CO2, PERMS, ws);
    hipLaunchKernelGGL(gram_mfma, dim3(224), dim3(256), 0, stream, ws, out);
    hipLaunchKernelGGL(loss_finish2, dim3(1), dim3(64), 0, stream, ws, out);
    hipLaunchKernelGGL(neg_loss_kernel, dim3(1024), dim3(256), 0, stream,
                       out + OFF_NEG_LOSS, out + OFF_NEG_CD, ws + WS_ADDT);
  } else {
    float* bsums = ws;
    float* addterm = bsums + 896 * 3;
    hipLaunchKernelGGL(loss_main_fb, dim3(896), dim3(256), 0, stream,
                       OF, OFP, OC, OCP, DAF, CO1, CO2, PERMS, out, bsums);
    hipLaunchKernelGGL(loss_finish_fb, dim3(1), dim3(64), 0, stream,
                       bsums, out, addterm);
    hipLaunchKernelGGL(neg_loss_fb, dim3(2048), dim3(256), 0, stream,
                       out + OFF_NEG_LOSS, out + OFF_NEG_CD, addterm);
  }
}

// Round 8
// 155.526 us; speedup vs baseline: 1.0863x; 1.0863x over previous
//
#include <hip/hip_runtime.h>

#define CF 768
#define CCODE 70
#define NPIX 784
#define P 121
#define NB 32
#define NTOTF 468512.0f

#define OFF_PI_SCALAR 0
#define OFF_PI_CD 1
#define OFF_PO_SCALAR 468513
#define OFF_PO_CD 468514
#define OFF_NEG_LOSS 937026
#define OFF_NEG_CD 3279586

// ---- ws layout (floats) ----
#define WS_BSUMS 0             // 224*3
#define WS_ADDT 768            // 5
#define WS_INVF 1024           // 8 slots * 32 n * 128 pt = 32768
#define WS_INVC 33792          // 7 slots * 32 n * 128 pt = 28672
#define WS_FRAG_FLOAT 62464    // bf16 fragment region starts here
#define FEAT_FRAG_SHORTS 98304 // 24 panels * 8 tiles * 64 lanes * 8
#define CODE_FRAG_SHORTS 12288 // 3 panels * 8 * 64 * 8
#define FEATS_TOTAL_SHORTS (8 * 32 * FEAT_FRAG_SHORTS)
#define CODE_BASE_SHORTS FEATS_TOTAL_SHORTS
#define CODE_TOTAL_SHORTS (7 * 32 * CODE_FRAG_SHORTS)
#define WS_NEED2 (WS_FRAG_FLOAT + (FEATS_TOTAL_SHORTS + CODE_TOTAL_SHORTS) / 2)

typedef __attribute__((ext_vector_type(8))) short short8;
typedef __attribute__((ext_vector_type(4))) float f32x4;
typedef unsigned short ushort_t;
typedef unsigned int uint_t;

__device__ __forceinline__ float samp4(const float* __restrict__ img, int c,
                                       const int4 o, const float4 w) {
  const float* p = img + c * NPIX;
  return w.x * p[o.x] + w.y * p[o.y] + w.z * p[o.z] + w.w * p[o.w];
}

__device__ __forceinline__ void mkcoord(const float* cp, int4* o, float4* w) {
  float x = fminf(fmaxf(cp[0] * 27.f, 0.f), 27.f);
  float y = fminf(fmaxf(cp[1] * 27.f, 0.f), 27.f);
  float x0f = floorf(x), y0f = floorf(y);
  int x0 = (int)x0f, y0 = (int)y0f;
  int x1 = min(x0 + 1, 27), y1 = min(y0 + 1, 27);
  float wx = x - x0f, wy = y - y0f;
  *o = make_int4(y0 * 28 + x0, y0 * 28 + x1, y1 * 28 + x0, y1 * 28 + x1);
  *w = make_float4((1.f - wx) * (1.f - wy), wx * (1.f - wy),
                   (1.f - wx) * wy, wx * wy);
}

// pair-based coords: o = (row0 base, row1 base), w = (wa0, wa1, wb0, wb1)
// value = wa0*p[o.x] + wa1*p[o.x+1] + wb0*p[o.y] + wb1*p[o.y+1]
__device__ __forceinline__ void mkcoord2(const float* cp, int2* o, float4* w) {
  float x = fminf(fmaxf(cp[0] * 27.f, 0.f), 27.f);
  float y = fminf(fmaxf(cp[1] * 27.f, 0.f), 27.f);
  float x0f = floorf(x), y0f = floorf(y);
  int x0 = (int)x0f, y0 = (int)y0f;
  int y1 = min(y0 + 1, 27);
  float wx = x - x0f, wy = y - y0f;
  bool sh = (x0 >= 27);
  int xb = sh ? 26 : x0;
  float wa0 = sh ? 0.f : (1.f - wx) * (1.f - wy);
  float wa1 = sh ? (1.f - wy) : wx * (1.f - wy);
  float wb0 = sh ? 0.f : (1.f - wx) * wy;
  float wb1 = sh ? wy : wx * wy;
  *o = make_int2(y0 * 28 + xb, y1 * 28 + xb);
  *w = make_float4(wa0, wa1, wb0, wb1);
}

__device__ __forceinline__ ushort_t f2bf(float x) {
  uint_t u = __float_as_uint(x);
  u += 0x7fffu + ((u >> 16) & 1u);
  return (ushort_t)(u >> 16);
}

__device__ __forceinline__ float bflo(uint_t u) {
  return __uint_as_float(u << 16);
}
__device__ __forceinline__ float bfhi(uint_t u) {
  return __uint_as_float(u & 0xffff0000u);
}

// ===================== image-centric presample =====================
// Block = (tensor, image m, octet o of 8 channels). Stage 8 planes into LDS
// coalesced, then sample every coordset referencing this image. The perms are
// NOT bijections (p+1 bump can duplicate values), so each block scans all
// (i,k) for PERMS[i][k]==m; each value appears <=2x per perm => <=11 coordsets.
// Every (slot,n) frag entry is written exactly once across all blocks.
// Frag layout per (slot,n): ((kp*8 + tile)*64 + lane)*8 + i (bf16),
// lane = lg*16+(pt&15), channel = kp*32 + lg*8 + i, point = tile*16+(pt&15);
// o = kp*4+lg.
// jobs: [0,3072) OF; [3072,6144) DAF; [6144,9216) OFP; [9216,9600) OC;
// [9600,9984) OCP.
__global__ __launch_bounds__(256) void presample_img(
    const float* __restrict__ OF, const float* __restrict__ OFP,
    const float* __restrict__ OC, const float* __restrict__ OCP,
    const float* __restrict__ DAF,
    const float* __restrict__ CO1, const float* __restrict__ CO2,
    const int* __restrict__ PERMS, float* __restrict__ ws) {
  ushort_t* frags = (ushort_t*)(ws + WS_FRAG_FLOAT);
  __shared__ float planes[8 * NPIX];  // 25088 B
  __shared__ int sh_slot[16], sh_n[16], sh_cb[16];
  __shared__ int sh_ncs;
  const int job = blockIdx.x, tid = threadIdx.x;

  int tensor, m, o;
  if (job < 3072) { tensor = 0; m = job / 96; o = job - m * 96; }
  else if (job < 6144) { int j = job - 3072; tensor = 1; m = j / 96; o = j - m * 96; }
  else if (job < 9216) { int j = job - 6144; tensor = 2; m = j / 96; o = j - m * 96; }
  else if (job < 9600) { int j = job - 9216; tensor = 3; m = j / 12; o = j - m * 12; }
  else { int j = job - 9600; tensor = 4; m = j / 12; o = j - m * 12; }

  const float* src;
  int nch;
  bool feat;
  if (tensor == 0) { src = OF + (size_t)m * CF * NPIX; nch = CF; feat = true; }
  else if (tensor == 1) { src = DAF + (size_t)m * CF * NPIX; nch = CF; feat = true; }
  else if (tensor == 2) { src = OFP + (size_t)m * CF * NPIX; nch = CF; feat = true; }
  else if (tensor == 3) { src = OC + (size_t)m * CCODE * NPIX; nch = CCODE; feat = false; }
  else { src = OCP + (size_t)m * CCODE * NPIX; nch = CCODE; feat = false; }

  // ---- coordset list (thread 0; overlaps with staging by other threads) ----
  if (tid == 0) {
    int cnt = 0;
    if (tensor == 0) {
      sh_slot[0] = 1; sh_n[0] = m; sh_cb[0] = 0; cnt = 1;
      for (int i = 0; i < 5; ++i)
        for (int k = 0; k < NB; ++k)
          if (PERMS[i * NB + k] == m) {
            sh_slot[cnt] = 3 + i; sh_n[cnt] = k; sh_cb[cnt] = 1; ++cnt;
          }
    } else if (tensor == 1) { sh_slot[0] = 0; sh_n[0] = m; sh_cb[0] = 0; cnt = 1; }
    else if (tensor == 2) { sh_slot[0] = 2; sh_n[0] = m; sh_cb[0] = 1; cnt = 1; }
    else if (tensor == 3) {
      sh_slot[0] = 0; sh_n[0] = m; sh_cb[0] = 0; cnt = 1;
      for (int i = 0; i < 5; ++i)
        for (int k = 0; k < NB; ++k)
          if (PERMS[i * NB + k] == m) {
            sh_slot[cnt] = 2 + i; sh_n[cnt] = k; sh_cb[cnt] = 1; ++cnt;
          }
    } else { sh_slot[0] = 1; sh_n[0] = m; sh_cb[0] = 1; cnt = 1; }
    sh_ncs = cnt;
  }

  // ---- stage 8 planes (zero-fill beyond valid channels) ----
  const int c0 = o * 8;
  {
    int valid = nch - c0;
    valid = valid > 8 ? 8 : (valid < 0 ? 0 : valid);
    const float* sc = src + (size_t)c0 * NPIX;
    const int lim4 = valid * (NPIX / 4);
    for (int e = tid; e < 8 * NPIX / 4; e += 256) {
      float4 v = (e < lim4) ? ((const float4*)sc)[e]
                            : make_float4(0.f, 0.f, 0.f, 0.f);
      ((float4*)planes)[e] = v;
    }
  }
  __syncthreads();

  // ---- sample from LDS, pack bf16, write frags ----
  const int kp = o >> 2, lg = o & 3;
  const int total = sh_ncs * 128;
  for (int s = tid; s < total; s += 256) {
    const int cs = s >> 7, pt = s & 127;
    const int slot = sh_slot[cs], n = sh_n[cs];
    const float* cb = sh_cb[cs] ? CO2 : CO1;
    float v[8];
    if (pt < P) {
      int gi = pt / 11, gj = pt - gi * 11;
      int2 o2;
      float4 w4;
      mkcoord2(cb + (((n * 11 + gj) * 11 + gi) << 1), &o2, &w4);
#pragma unroll
      for (int i = 0; i < 8; ++i) {
        const float* pl = planes + i * NPIX;
        v[i] = w4.x * pl[o2.x] + w4.y * pl[o2.x + 1] + w4.z * pl[o2.y] +
               w4.w * pl[o2.y + 1];
      }
    } else {
#pragma unroll
      for (int i = 0; i < 8; ++i) v[i] = 0.f;
    }
    uint4 q;
    q.x = (uint_t)f2bf(v[0]) | ((uint_t)f2bf(v[1]) << 16);
    q.y = (uint_t)f2bf(v[2]) | ((uint_t)f2bf(v[3]) << 16);
    q.z = (uint_t)f2bf(v[4]) | ((uint_t)f2bf(v[5]) << 16);
    q.w = (uint_t)f2bf(v[6]) | ((uint_t)f2bf(v[7]) << 16);
    size_t fragbase = feat ? (size_t)(slot * 32 + n) * FEAT_FRAG_SHORTS
                           : CODE_BASE_SHORTS + (size_t)(slot * 32 + n) * CODE_FRAG_SHORTS;
    *(uint4*)(frags + fragbase +
              ((size_t)((kp * 8 + (pt >> 4)) * 64 + lg * 16 + (pt & 15)) << 3)) = q;
  }
}

// ===================== norms from bf16 frags =====================
// blocks 0..255: feat (slot=b>>5, n=b&31); 256..479: code.
__global__ __launch_bounds__(128) void norms_kernel(float* __restrict__ ws) {
  const ushort_t* frags = (const ushort_t*)(ws + WS_FRAG_FLOAT);
  const int b = blockIdx.x, p = threadIdx.x;
  float s = 0.f;
  if (b < 256) {
    const int slot = b >> 5, n = b & 31;
    const uint4* F = (const uint4*)(frags + (size_t)(slot * 32 + n) * FEAT_FRAG_SHORTS);
    for (int kp = 0; kp < 24; ++kp) {
#pragma unroll
      for (int lg = 0; lg < 4; ++lg) {
        uint4 q = F[(kp * 8 + (p >> 4)) * 64 + lg * 16 + (p & 15)];
        float a;
        a = bflo(q.x); s = fmaf(a, a, s); a = bfhi(q.x); s = fmaf(a, a, s);
        a = bflo(q.y); s = fmaf(a, a, s); a = bfhi(q.y); s = fmaf(a, a, s);
        a = bflo(q.z); s = fmaf(a, a, s); a = bfhi(q.z); s = fmaf(a, a, s);
        a = bflo(q.w); s = fmaf(a, a, s); a = bfhi(q.w); s = fmaf(a, a, s);
      }
    }
    ws[WS_INVF + (slot * 32 + n) * 128 + p] = 1.f / fmaxf(sqrtf(s), 1e-10f);
  } else {
    const int b2 = b - 256;
    const int slot = b2 >> 5, n = b2 & 31;
    const uint4* F = (const uint4*)(frags + CODE_BASE_SHORTS +
                                    (size_t)(slot * 32 + n) * CODE_FRAG_SHORTS);
#pragma unroll
    for (int kp = 0; kp < 3; ++kp) {
#pragma unroll
      for (int lg = 0; lg < 4; ++lg) {
        uint4 q = F[(kp * 8 + (p >> 4)) * 64 + lg * 16 + (p & 15)];
        float a;
        a = bflo(q.x); s = fmaf(a, a, s); a = bfhi(q.x); s = fmaf(a, a, s);
        a = bflo(q.y); s = fmaf(a, a, s); a = bfhi(q.y); s = fmaf(a, a, s);
        a = bflo(q.z); s = fmaf(a, a, s); a = bfhi(q.z); s = fmaf(a, a, s);
        a = bflo(q.w); s = fmaf(a, a, s); a = bfhi(q.w); s = fmaf(a, a, s);
      }
    }
    ws[WS_INVC + (slot * 32 + n) * 128 + p] = 1.f / fmaxf(sqrtf(s), 1e-10f);
  }
}

// ===================== MFMA Gram =====================
__global__ __launch_bounds__(256) void gram_mfma(float* __restrict__ ws,
                                                 float* __restrict__ out) {
  const ushort_t* frags = (const ushort_t*)(ws + WS_FRAG_FLOAT);
  const int bid = blockIdx.x, pair = bid >> 5, n = bid & 31;
  const int tid = threadIdx.x, wave = tid >> 6, lane = tid & 63;
  __shared__ float invAf[128], invBf[128], invAc[128], invBc[128];
  __shared__ float red[4][3];
  const int afslot = (pair == 0) ? 0 : 1;
  const int bfslot = (pair == 0) ? 0 : (pair == 1 ? 2 : 3 + (pair - 2));
  const int bcslot = (pair == 0) ? 0 : (pair == 1 ? 1 : 2 + (pair - 2));
  if (tid < 128) {
    invAf[tid] = ws[WS_INVF + (afslot * 32 + n) * 128 + tid];
    invBf[tid] = ws[WS_INVF + (bfslot * 32 + n) * 128 + tid];
    invAc[tid] = ws[WS_INVC + (0 * 32 + n) * 128 + tid];
    invBc[tid] = ws[WS_INVC + (bcslot * 32 + n) * 128 + tid];
  }
  __syncthreads();

  const short8* Af = (const short8*)(frags + (size_t)(afslot * 32 + n) * FEAT_FRAG_SHORTS);
  const short8* Bf = (const short8*)(frags + (size_t)(bfslot * 32 + n) * FEAT_FRAG_SHORTS);

  f32x4 acc[2][8];
#pragma unroll
  for (int j = 0; j < 2; ++j)
#pragma unroll
    for (int t = 0; t < 8; ++t) acc[j][t] = (f32x4){0.f, 0.f, 0.f, 0.f};

#pragma unroll 2
  for (int kp = 0; kp < 24; ++kp) {
    short8 a0 = Af[(kp * 8 + 2 * wave) * 64 + lane];
    short8 a1 = Af[(kp * 8 + 2 * wave + 1) * 64 + lane];
    short8 bv[8];
#pragma unroll
    for (int t = 0; t < 8; ++t) bv[t] = Bf[(kp * 8 + t) * 64 + lane];
#pragma unroll
    for (int t = 0; t < 8; ++t) {
      acc[0][t] = __builtin_amdgcn_mfma_f32_16x16x32_bf16(a0, bv[t], acc[0][t], 0, 0, 0);
      acc[1][t] = __builtin_amdgcn_mfma_f32_16x16x32_bf16(a1, bv[t], acc[1][t], 0, 0, 0);
    }
  }

  // ---- feats epilogue: normalize, row-center (fd kept in acc) ----
  const int lane4 = (lane >> 4) << 2;
  const int cl15 = lane & 15;
  float sfd = 0.f;
#pragma unroll
  for (int j = 0; j < 2; ++j) {
    const int rb = (2 * wave + j) * 16 + lane4;
    const float ivr0 = invAf[rb], ivr1 = invAf[rb + 1], ivr2 = invAf[rb + 2],
                ivr3 = invAf[rb + 3];
    float rs0 = 0.f, rs1 = 0.f, rs2 = 0.f, rs3 = 0.f;
#pragma unroll
    for (int t = 0; t < 8; ++t) {
      const float ivc = invBf[t * 16 + cl15];
      float v0 = acc[j][t].x * ivr0 * ivc;
      float v1 = acc[j][t].y * ivr1 * ivc;
      float v2 = acc[j][t].z * ivr2 * ivc;
      float v3 = acc[j][t].w * ivr3 * ivc;
      acc[j][t].x = v0; acc[j][t].y = v1; acc[j][t].z = v2; acc[j][t].w = v3;
      rs0 += v0; rs1 += v1; rs2 += v2; rs3 += v3;
    }
    sfd += rs0 + rs1 + rs2 + rs3;
    rs0 += __shfl_xor(rs0, 1); rs0 += __shfl_xor(rs0, 2);
    rs0 += __shfl_xor(rs0, 4); rs0 += __shfl_xor(rs0, 8);
    rs1 += __shfl_xor(rs1, 1); rs1 += __shfl_xor(rs1, 2);
    rs1 += __shfl_xor(rs1, 4); rs1 += __shfl_xor(rs1, 8);
    rs2 += __shfl_xor(rs2, 1); rs2 += __shfl_xor(rs2, 2);
    rs2 += __shfl_xor(rs2, 4); rs2 += __shfl_xor(rs2, 8);
    rs3 += __shfl_xor(rs3, 1); rs3 += __shfl_xor(rs3, 2);
    rs3 += __shfl_xor(rs3, 4); rs3 += __shfl_xor(rs3, 8);
    const float rm0 = rs0 * (1.f / 121.f), rm1 = rs1 * (1.f / 121.f);
    const float rm2 = rs2 * (1.f / 121.f), rm3 = rs3 * (1.f / 121.f);
#pragma unroll
    for (int t = 0; t < 8; ++t) {
      acc[j][t].x -= rm0; acc[j][t].y -= rm1; acc[j][t].z -= rm2; acc[j][t].w -= rm3;
    }
  }

  int cd_base, loss_base = 0;
  if (pair == 0) cd_base = OFF_PI_CD + n * 14641;
  else if (pair == 1) cd_base = OFF_PO_CD + n * 14641;
  else {
    int t0 = ((pair - 2) * NB + n) * 14641;
    cd_base = OFF_NEG_CD + t0;
    loss_base = OFF_NEG_LOSS + t0;
  }

  if (pair >= 2) {
#pragma unroll
    for (int j = 0; j < 2; ++j) {
      const int rb = (2 * wave + j) * 16 + lane4;
      if (rb < P) {
#pragma unroll
        for (int t = 0; t < 8; ++t) {
          const int c = t * 16 + cl15;
          if (c < P) {
            float* o = out + loss_base + rb * P + c;
            o[0] = acc[j][t].x;
            if (rb + 1 < P) o[P] = acc[j][t].y;
            if (rb + 2 < P) o[2 * P] = acc[j][t].z;
            if (rb + 3 < P) o[3 * P] = acc[j][t].w;
          }
        }
      }
    }
  }

  // ---- code Gram ----
  const short8* Ac = (const short8*)(frags + CODE_BASE_SHORTS + (size_t)n * CODE_FRAG_SHORTS);
  const short8* Bc = (const short8*)(frags + CODE_BASE_SHORTS + (size_t)(bcslot * 32 + n) * CODE_FRAG_SHORTS);
  f32x4 cacc[2][8];
#pragma unroll
  for (int j = 0; j < 2; ++j)
#pragma unroll
    for (int t = 0; t < 8; ++t) cacc[j][t] = (f32x4){0.f, 0.f, 0.f, 0.f};
#pragma unroll
  for (int kp = 0; kp < 3; ++kp) {
    short8 a0 = Ac[(kp * 8 + 2 * wave) * 64 + lane];
    short8 a1 = Ac[(kp * 8 + 2 * wave + 1) * 64 + lane];
    short8 bv[8];
#pragma unroll
    for (int t = 0; t < 8; ++t) bv[t] = Bc[(kp * 8 + t) * 64 + lane];
#pragma unroll
    for (int t = 0; t < 8; ++t) {
      cacc[0][t] = __builtin_amdgcn_mfma_f32_16x16x32_bf16(a0, bv[t], cacc[0][t], 0, 0, 0);
      cacc[1][t] = __builtin_amdgcn_mfma_f32_16x16x32_bf16(a1, bv[t], cacc[1][t], 0, 0, 0);
    }
  }

  float s1 = 0.f, s2 = 0.f;
#pragma unroll
  for (int j = 0; j < 2; ++j) {
    const int rb = (2 * wave + j) * 16 + lane4;
    const float ivr0 = invAc[rb], ivr1 = invAc[rb + 1], ivr2 = invAc[rb + 2],
                ivr3 = invAc[rb + 3];
#pragma unroll
    for (int t = 0; t < 8; ++t) {
      const int c = t * 16 + cl15;
      const float ivc = invBc[c];
      float c0v = cacc[j][t].x * ivr0 * ivc;
      float c1v = cacc[j][t].y * ivr1 * ivc;
      float c2v = cacc[j][t].z * ivr2 * ivc;
      float c3v = cacc[j][t].w * ivr3 * ivc;
      if (c < P && rb < P) {
        float* o = out + cd_base + rb * P + c;
        o[0] = c0v;
        if (rb + 1 < P) o[P] = c1v;
        if (rb + 2 < P) o[2 * P] = c2v;
        if (rb + 3 < P) o[3 * P] = c3v;
      }
      if (pair < 2) {
        float cl0 = fminf(fmaxf(c0v, 0.f), 0.8f);
        float cl1 = fminf(fmaxf(c1v, 0.f), 0.8f);
        float cl2 = fminf(fmaxf(c2v, 0.f), 0.8f);
        float cl3 = fminf(fmaxf(c3v, 0.f), 0.8f);
        s1 = fmaf(cl0, acc[j][t].x, s1);
        s1 = fmaf(cl1, acc[j][t].y, s1);
        s1 = fmaf(cl2, acc[j][t].z, s1);
        s1 = fmaf(cl3, acc[j][t].w, s1);
        s2 += cl0 + cl1 + cl2 + cl3;
      }
    }
  }

#pragma unroll
  for (int m = 1; m < 64; m <<= 1) {
    sfd += __shfl_xor(sfd, m);
    s1 += __shfl_xor(s1, m);
    s2 += __shfl_xor(s2, m);
  }
  if ((tid & 63) == 0) { red[wave][0] = sfd; red[wave][1] = s1; red[wave][2] = s2; }
  __syncthreads();
  if (tid == 0) {
    float a = 0.f, b2 = 0.f, c2 = 0.f;
    for (int w = 0; w < 4; ++w) { a += red[w][0]; b2 += red[w][1]; c2 += red[w][2]; }
    float* bsums = ws + WS_BSUMS;
    bsums[bid * 3 + 0] = a;
    bsums[bid * 3 + 1] = b2;
    bsums[bid * 3 + 2] = c2;
  }
}

__global__ void loss_finish2(float* __restrict__ ws, float* __restrict__ out) {
  __shared__ float s[7][3];
  const float* bsums = ws + WS_BSUMS;
  float* addterm = ws + WS_ADDT;
  int tid = threadIdx.x;
  if (tid < 21) {
    int pr = tid / 3, k = tid % 3;
    float a = 0.f;
    for (int i = 0; i < 32; ++i) a += bsums[(pr * 32 + i) * 3 + k];
    s[pr][k] = a;
  }
  __syncthreads();
  if (tid == 0) {
    const float invN = 1.f / NTOTF;
    out[OFF_PI_SCALAR] = -(s[0][1] + (s[0][0] * invN - 0.18f) * s[0][2]) * invN;
    out[OFF_PO_SCALAR] = -(s[1][1] + (s[1][0] * invN - 0.12f) * s[1][2]) * invN;
  }
  if (tid >= 1 && tid < 6) addterm[tid - 1] = s[tid + 1][0] / NTOTF - 0.46f;
}

__global__ __launch_bounds__(256) void neg_loss_kernel(
    float* __restrict__ lossr, const float* __restrict__ cdr,
    const float* __restrict__ addterm) {
  __shared__ float at[5];
  if (threadIdx.x < 5) at[threadIdx.x] = addterm[threadIdx.x];
  __syncthreads();
  const int total4 = 5 * 117128;  // 468512/4 per pair
  float4* l4 = (float4*)lossr;
  const float4* c4 = (const float4*)cdr;
  for (int e = blockIdx.x * 256 + threadIdx.x; e < total4; e += gridDim.x * 256) {
    int k = e / 117128;
    float4 cd = c4[e];
    float4 fv = l4[e];
    float a = at[k];
    float4 r;
    r.x = -fminf(fmaxf(cd.x, 0.f), 0.8f) * (fv.x + a);
    r.y = -fminf(fmaxf(cd.y, 0.f), 0.8f) * (fv.y + a);
    r.z = -fminf(fmaxf(cd.z, 0.f), 0.8f) * (fv.z + a);
    r.w = -fminf(fmaxf(cd.w, 0.f), 0.8f) * (fv.w + a);
    l4[e] = r;
  }
}

// ===================== fallback path (round-1, verified) =====================

__global__ __launch_bounds__(256) void loss_main_fb(
    const float* __restrict__ OF, const float* __restrict__ OFP,
    const float* __restrict__ OC, const float* __restrict__ OCP,
    const float* __restrict__ DAF,
    const float* __restrict__ CO1, const float* __restrict__ CO2,
    const int* __restrict__ PERMS,
    float* __restrict__ out, float* __restrict__ bsums) {
  const int b = blockIdx.x;
  const int pair = b >> 7;
  const int rem = b & 127;
  const int n = rem >> 2;
  const int rg = rem & 3;
  const int row_start = rg * 31;
  const int rcount = min(31, P - row_start);
  const int tid = threadIdx.x;
  const int tx = tid & 15, ty = tid >> 4;

  const float *F1, *F2, *C1, *C2, *CB;
  if (pair == 0) {
    F1 = DAF + (size_t)n * CF * NPIX; F2 = F1;
    C1 = OC + (size_t)n * CCODE * NPIX; C2 = C1;
    CB = CO1;
  } else if (pair == 1) {
    F1 = OF + (size_t)n * CF * NPIX; F2 = OFP + (size_t)n * CF * NPIX;
    C1 = OC + (size_t)n * CCODE * NPIX; C2 = OCP + (size_t)n * CCODE * NPIX;
    CB = CO2;
  } else {
    int n2 = PERMS[(pair - 2) * NB + n];
    F1 = OF + (size_t)n * CF * NPIX; F2 = OF + (size_t)n2 * CF * NPIX;
    C1 = OC + (size_t)n * CCODE * NPIX; C2 = OC + (size_t)n2 * CCODE * NPIX;
    CB = CO2;
  }

  __shared__ int4 Bo[P];
  __shared__ float4 Bw[P];
  __shared__ int4 Ao[32];
  __shared__ float4 Aw[32];
  __shared__ float Abuf[CCODE][32];
  __shared__ float Bbuf[CCODE][128];
  __shared__ float invA[32], invB[128];
  __shared__ float red[4][3];

  if (tid < P) {
    int gi = tid / 11, gj = tid - gi * 11;
    const float* cp = CB + (((n * 11 + gj) * 11 + gi) << 1);
    mkcoord(cp, &Bo[tid], &Bw[tid]);
  } else if (tid >= 128 && tid < 160) {
    int r = tid - 128;
    int q = row_start + r;
    if (q < P) {
      int gi = q / 11, gj = q - gi * 11;
      const float* cp = CO1 + (((n * 11 + gj) * 11 + gi) << 1);
      mkcoord(cp, &Ao[r], &Aw[r]);
    }
  }
  __syncthreads();

  float acc[2][2][4];
#pragma unroll
  for (int kr = 0; kr < 2; ++kr)
#pragma unroll
    for (int m = 0; m < 2; ++m)
#pragma unroll
      for (int u = 0; u < 4; ++u) acc[kr][m][u] = 0.f;
  float ansq = 0.f, bnsq = 0.f;

  for (int ch = 0; ch < 12; ++ch) {
    const int c0 = ch * 64;
    if (ch) __syncthreads();
    for (int e = tid; e < 64 * 128; e += 256) {
      int col = e & 127, cc = e >> 7;
      float v = 0.f;
      if (col < P) v = samp4(F2, c0 + cc, Bo[col], Bw[col]);
      Bbuf[cc][col] = v;
    }
    for (int e = tid; e < 64 * 32; e += 256) {
      int col = e & 31, cc = e >> 5;
      float v = 0.f;
      if (col < rcount) v = samp4(F1, c0 + cc, Ao[col], Aw[col]);
      Abuf[cc][col] = v;
    }
    __syncthreads();
    if (tid < 128) {
      float s = 0.f;
      for (int cc = 0; cc < 64; ++cc) { float v = Bbuf[cc][tid]; s = fmaf(v, v, s); }
      bnsq += s;
    } else if (tid < 160) {
      int r = tid - 128;
      float s = 0.f;
      for (int cc = 0; cc < 64; ++cc) { float v = Abuf[cc][r]; s = fmaf(v, v, s); }
      ansq += s;
    }
    for (int cc = 0; cc < 64; ++cc) {
      const float2 av = *(const float2*)&Abuf[cc][ty * 2];
      const float4 b0 = *(const float4*)&Bbuf[cc][tx * 4];
      const float4 b1 = *(const float4*)&Bbuf[cc][tx * 4 + 64];
      float a[2] = {av.x, av.y};
      float bb[2][4] = {{b0.x, b0.y, b0.z, b0.w}, {b1.x, b1.y, b1.z, b1.w}};
#pragma unroll
      for (int kr = 0; kr < 2; ++kr)
#pragma unroll
        for (int m = 0; m < 2; ++m)
#pragma unroll
          for (int u = 0; u < 4; ++u)
            acc[kr][m][u] = fmaf(a[kr], bb[m][u], acc[kr][m][u]);
    }
  }
  __syncthreads();
  if (tid < 128) invB[tid] = (tid < P) ? 1.f / fmaxf(sqrtf(bnsq), 1e-10f) : 0.f;
  else if (tid < 160) {
    int r = tid - 128;
    invA[r] = (r < rcount) ? 1.f / fmaxf(sqrtf(ansq), 1e-10f) : 0.f;
  }
  __syncthreads();

  float ia[2] = {invA[2 * ty], invA[2 * ty + 1]};
  float ib[2][4];
#pragma unroll
  for (int m = 0; m < 2; ++m)
#pragma unroll
    for (int u = 0; u < 4; ++u) ib[m][u] = invB[m * 64 + tx * 4 + u];

  float fdc[2][2][4];
  float sfd = 0.f;
#pragma unroll
  for (int kr = 0; kr < 2; ++kr) {
    float part = 0.f;
#pragma unroll
    for (int m = 0; m < 2; ++m)
#pragma unroll
      for (int u = 0; u < 4; ++u) {
        float v = acc[kr][m][u] * ia[kr] * ib[m][u];
        fdc[kr][m][u] = v;
        part += v;
      }
    sfd += part;
    float rs = part;
#pragma unroll
    for (int s = 1; s < 16; s <<= 1) rs += __shfl_xor(rs, s, 16);
    float rowm = rs * (1.f / 121.f);
#pragma unroll
    for (int m = 0; m < 2; ++m)
#pragma unroll
      for (int u = 0; u < 4; ++u) fdc[kr][m][u] -= rowm;
  }
  __syncthreads();

  for (int e = tid; e < CCODE * 128; e += 256) {
    int col = e & 127, cc = e >> 7;
    float v = 0.f;
    if (col < P) v = samp4(C2, cc, Bo[col], Bw[col]);
    Bbuf[cc][col] = v;
  }
  for (int e = tid; e < CCODE * 32; e += 256) {
    int col = e & 31, cc = e >> 5;
    float v = 0.f;
    if (col < rcount) v = samp4(C1, cc, Ao[col], Aw[col]);
    Abuf[cc][col] = v;
  }
  __syncthreads();
  if (tid < 128) {
    float s = 0.f;
    for (int cc = 0; cc < CCODE; ++cc) { float v = Bbuf[cc][tid]; s = fmaf(v, v, s); }
    invB[tid] = (tid < P) ? 1.f / fmaxf(sqrtf(s), 1e-10f) : 0.f;
  } else if (tid < 160) {
    int r = tid - 128;
    float s = 0.f;
    for (int cc = 0; cc < CCODE; ++cc) { float v = Abuf[cc][r]; s = fmaf(v, v, s); }
    invA[r] = (r < rcount) ? 1.f / fmaxf(sqrtf(s), 1e-10f) : 0.f;
  }
  float cacc[2][2][4];
#pragma unroll
  for (int kr = 0; kr < 2; ++kr)
#pragma unroll
    for (int m = 0; m < 2; ++m)
#pragma unroll
      for (int u = 0; u < 4; ++u) cacc[kr][m][u] = 0.f;
  for (int cc = 0; cc < CCODE; ++cc) {
    const float2 av = *(const float2*)&Abuf[cc][ty * 2];
    const float4 b0 = *(const float4*)&Bbuf[cc][tx * 4];
    const float4 b1 = *(const float4*)&Bbuf[cc][tx * 4 + 64];
    float a[2] = {av.x, av.y};
    float bb[2][4] = {{b0.x, b0.y, b0.z, b0.w}, {b1.x, b1.y, b1.z, b1.w}};
#pragma unroll
    for (int kr = 0; kr < 2; ++kr)
#pragma unroll
      for (int m = 0; m < 2; ++m)
#pragma unroll
        for (int u = 0; u < 4; ++u)
          cacc[kr][m][u] = fmaf(a[kr], bb[m][u], cacc[kr][m][u]);
  }
  __syncthreads();
  float iac[2] = {invA[2 * ty], invA[2 * ty + 1]};
  float ibc[2][4];
#pragma unroll
  for (int m = 0; m < 2; ++m)
#pragma unroll
    for (int u = 0; u < 4; ++u) ibc[m][u] = invB[m * 64 + tx * 4 + u];

  int cd_base, loss_base = 0;
  if (pair == 0) cd_base = OFF_PI_CD + n * 14641;
  else if (pair == 1) cd_base = OFF_PO_CD + n * 14641;
  else {
    int t = ((pair - 2) * NB + n) * 14641;
    cd_base = OFF_NEG_CD + t;
    loss_base = OFF_NEG_LOSS + t;
  }

  float s1 = 0.f, s2 = 0.f;
#pragma unroll
  for (int kr = 0; kr < 2; ++kr) {
    int r = 2 * ty + kr;
    if (r < rcount) {
      int rglob = row_start + r;
#pragma unroll
      for (int m = 0; m < 2; ++m)
#pragma unroll
        for (int u = 0; u < 4; ++u) {
          int c = m * 64 + tx * 4 + u;
          if (c < P) {
            float cdv = cacc[kr][m][u] * iac[kr] * ibc[m][u];
            int idx = rglob * P + c;
            out[cd_base + idx] = cdv;
            float cl = fminf(fmaxf(cdv, 0.f), 0.8f);
            float fv = fdc[kr][m][u];
            if (pair < 2) { s1 = fmaf(cl, fv, s1); s2 += cl; }
            else out[loss_base + idx] = fv;
          }
        }
    }
  }

#pragma unroll
  for (int s = 1; s < 64; s <<= 1) {
    sfd += __shfl_xor(sfd, s);
    s1 += __shfl_xor(s1, s);
    s2 += __shfl_xor(s2, s);
  }
  int wv = tid >> 6;
  if ((tid & 63) == 0) { red[wv][0] = sfd; red[wv][1] = s1; red[wv][2] = s2; }
  __syncthreads();
  if (tid == 0) {
    float a = 0.f, bb = 0.f, cc = 0.f;
    for (int w = 0; w < 4; ++w) { a += red[w][0]; bb += red[w][1]; cc += red[w][2]; }
    bsums[b * 3 + 0] = a;
    bsums[b * 3 + 1] = bb;
    bsums[b * 3 + 2] = cc;
  }
}

__global__ void loss_finish_fb(const float* __restrict__ bsums,
                               float* __restrict__ out,
                               float* __restrict__ addterm) {
  __shared__ float s[7][3];
  int tid = threadIdx.x;
  if (tid < 21) {
    int pr = tid / 3, k = tid % 3;
    float a = 0.f;
    const float* p = bsums + (pr * 128) * 3 + k;
    for (int i = 0; i < 128; ++i) a += p[i * 3];
    s[pr][k] = a;
  }
  __syncthreads();
  if (tid == 0) {
    const float invN = 1.f / NTOTF;
    out[OFF_PI_SCALAR] = -(s[0][1] + (s[0][0] * invN - 0.18f) * s[0][2]) * invN;
    out[OFF_PO_SCALAR] = -(s[1][1] + (s[1][0] * invN - 0.12f) * s[1][2]) * invN;
  }
  if (tid >= 1 && tid < 6) addterm[tid - 1] = s[tid + 1][0] / NTOTF - 0.46f;
}

__global__ __launch_bounds__(256) void neg_loss_fb(
    float* __restrict__ lossr, const float* __restrict__ cdr,
    const float* __restrict__ addterm) {
  __shared__ float at[5];
  if (threadIdx.x < 5) at[threadIdx.x] = addterm[threadIdx.x];
  __syncthreads();
  const int total = 5 * 468512;
  for (int e = blockIdx.x * 256 + threadIdx.x; e < total; e += gridDim.x * 256) {
    int k = e / 468512;
    float cdv = cdr[e];
    float cl = fminf(fmaxf(cdv, 0.f), 0.8f);
    lossr[e] = -cl * (lossr[e] + at[k]);
  }
}

extern "C" void kernel_launch(void* const* d_in, const int* in_sizes, int n_in,
                              void* d_out, int out_size, void* d_ws,
                              size_t ws_size, hipStream_t stream) {
  const float* OF = (const float*)d_in[0];
  const float* OFP = (const float*)d_in[1];
  const float* OC = (const float*)d_in[4];
  const float* OCP = (const float*)d_in[5];
  const float* DAF = (const float*)d_in[6];
  const float* CO1 = (const float*)d_in[8];
  const float* CO2 = (const float*)d_in[9];
  const int* PERMS = (const int*)d_in[10];
  float* out = (float*)d_out;
  float* ws = (float*)d_ws;

  if (ws_size >= (size_t)WS_NEED2 * sizeof(float)) {
    hipLaunchKernelGGL(presample_img, dim3(9984), dim3(256), 0, stream,
                       OF, OFP, OC, OCP, DAF, CO1, CO2, PERMS, ws);
    hipLaunchKernelGGL(norms_kernel, dim3(480), dim3(128), 0, stream, ws);
    hipLaunchKernelGGL(gram_mfma, dim3(224), dim3(256), 0, stream, ws, out);
    hipLaunchKernelGGL(loss_finish2, dim3(1), dim3(64), 0, stream, ws, out);
    hipLaunchKernelGGL(neg_loss_kernel, dim3(1024), dim3(256), 0, stream,
                       out + OFF_NEG_LOSS, out + OFF_NEG_CD, ws + WS_ADDT);
  } else {
    float* bsums = ws;
    float* addterm = bsums + 896 * 3;
    hipLaunchKernelGGL(loss_main_fb, dim3(896), dim3(256), 0, stream,
                       OF, OFP, OC, OCP, DAF, CO1, CO2, PERMS, out, bsums);
    hipLaunchKernelGGL(loss_finish_fb, dim3(1), dim3(64), 0, stream,
                       bsums, out, addterm);
    hipLaunchKernelGGL(neg_loss_fb, dim3(2048), dim3(256), 0, stream,
                       out + OFF_NEG_LOSS, out + OFF_NEG_CD, addterm);
  }
}

// Round 9
// 147.795 us; speedup vs baseline: 1.1431x; 1.0523x over previous
//
#include <hip/hip_runtime.h>

#define CF 768
#define CCODE 70
#define NPIX 784
#define P 121
#define NB 32
#define NTOTF 468512.0f

#define OFF_PI_SCALAR 0
#define OFF_PI_CD 1
#define OFF_PO_SCALAR 468513
#define OFF_PO_CD 468514
#define OFF_NEG_LOSS 937026
#define OFF_NEG_CD 3279586

// ---- ws layout (floats) ----
#define WS_BSUMS 0             // 224*3
#define WS_ADDT 768            // 5
#define WS_INVF 1024           // 8 slots * 32 n * 128 pt = 32768
#define WS_INVC 33792          // 7 slots * 32 n * 128 pt = 28672
#define WS_FRAG_FLOAT 62464    // bf16 fragment region starts here
#define FEAT_FRAG_SHORTS 98304 // 24 panels * 8 tiles * 64 lanes * 8
#define CODE_FRAG_SHORTS 12288 // 3 panels * 8 * 64 * 8
#define FEATS_TOTAL_SHORTS (8 * 32 * FEAT_FRAG_SHORTS)
#define CODE_BASE_SHORTS FEATS_TOTAL_SHORTS
#define CODE_TOTAL_SHORTS (7 * 32 * CODE_FRAG_SHORTS)
#define WS_NEED2 (WS_FRAG_FLOAT + (FEATS_TOTAL_SHORTS + CODE_TOTAL_SHORTS) / 2)

typedef __attribute__((ext_vector_type(8))) short short8;
typedef __attribute__((ext_vector_type(4))) float f32x4;
typedef unsigned short ushort_t;
typedef unsigned int uint_t;

__device__ __forceinline__ float samp4(const float* __restrict__ img, int c,
                                       const int4 o, const float4 w) {
  const float* p = img + c * NPIX;
  return w.x * p[o.x] + w.y * p[o.y] + w.z * p[o.z] + w.w * p[o.w];
}

__device__ __forceinline__ void mkcoord(const float* cp, int4* o, float4* w) {
  float x = fminf(fmaxf(cp[0] * 27.f, 0.f), 27.f);
  float y = fminf(fmaxf(cp[1] * 27.f, 0.f), 27.f);
  float x0f = floorf(x), y0f = floorf(y);
  int x0 = (int)x0f, y0 = (int)y0f;
  int x1 = min(x0 + 1, 27), y1 = min(y0 + 1, 27);
  float wx = x - x0f, wy = y - y0f;
  *o = make_int4(y0 * 28 + x0, y0 * 28 + x1, y1 * 28 + x0, y1 * 28 + x1);
  *w = make_float4((1.f - wx) * (1.f - wy), wx * (1.f - wy),
                   (1.f - wx) * wy, wx * wy);
}

// pair-based coords: o = (row0 base, row1 base), w = (wa0, wa1, wb0, wb1)
// value = wa0*p[o.x] + wa1*p[o.x+1] + wb0*p[o.y] + wb1*p[o.y+1]
__device__ __forceinline__ void mkcoord2(const float* cp, int2* o, float4* w) {
  float x = fminf(fmaxf(cp[0] * 27.f, 0.f), 27.f);
  float y = fminf(fmaxf(cp[1] * 27.f, 0.f), 27.f);
  float x0f = floorf(x), y0f = floorf(y);
  int x0 = (int)x0f, y0 = (int)y0f;
  int y1 = min(y0 + 1, 27);
  float wx = x - x0f, wy = y - y0f;
  bool sh = (x0 >= 27);
  int xb = sh ? 26 : x0;
  float wa0 = sh ? 0.f : (1.f - wx) * (1.f - wy);
  float wa1 = sh ? (1.f - wy) : wx * (1.f - wy);
  float wb0 = sh ? 0.f : (1.f - wx) * wy;
  float wb1 = sh ? wy : wx * wy;
  *o = make_int2(y0 * 28 + xb, y1 * 28 + xb);
  *w = make_float4(wa0, wa1, wb0, wb1);
}

__device__ __forceinline__ ushort_t f2bf(float x) {
  uint_t u = __float_as_uint(x);
  u += 0x7fffu + ((u >> 16) & 1u);
  return (ushort_t)(u >> 16);
}

__device__ __forceinline__ float bflo(uint_t u) {
  return __uint_as_float(u << 16);
}
__device__ __forceinline__ float bfhi(uint_t u) {
  return __uint_as_float(u & 0xffff0000u);
}

// ===================== pipelined image-centric presample =====================
// Block = (tensor, image m, GROUP of 4 octets). Per octet: regs->LDS, barrier,
// then ISSUE next octet's global loads (into regs) BEFORE sampling current
// octet from LDS — HBM latency hides under sampling (T14 async-STAGE split).
// Perms are NOT bijections: block scans all (i,k) for PERMS[i][k]==m (each
// value <=2x per perm => <=11 coordsets); every (slot,n) written exactly once.
// Frag layout per (slot,n): ((kp*8 + tile)*64 + lane)*8 + i (bf16),
// lane = lg*16+(pt&15), channel = kp*32+lg*8+i, point = tile*16+(pt&15);
// octet o = kp*4+lg.
// jobs: [0,768) OF (m=j/24, g0=(j%24)*4); [768,1536) DAF; [1536,2304) OFP;
// [2304,2400) OC (m=/3, g0=(%3)*4); [2400,2496) OCP.
#define GOCT 4
__global__ __launch_bounds__(256) void presample_pipe(
    const float* __restrict__ OF, const float* __restrict__ OFP,
    const float* __restrict__ OC, const float* __restrict__ OCP,
    const float* __restrict__ DAF,
    const float* __restrict__ CO1, const float* __restrict__ CO2,
    const int* __restrict__ PERMS, float* __restrict__ ws) {
  ushort_t* frags = (ushort_t*)(ws + WS_FRAG_FLOAT);
  __shared__ float planes[8 * NPIX];  // 25088 B
  __shared__ int sh_slot[16], sh_n[16], sh_cb[16];
  __shared__ int sh_ncs;
  const int job = blockIdx.x, tid = threadIdx.x;

  int tensor, m, g0;
  if (job < 768) { tensor = 0; m = job / 24; g0 = (job - m * 24) * 4; }
  else if (job < 1536) { int j = job - 768; tensor = 1; m = j / 24; g0 = (j - m * 24) * 4; }
  else if (job < 2304) { int j = job - 1536; tensor = 2; m = j / 24; g0 = (j - m * 24) * 4; }
  else if (job < 2400) { int j = job - 2304; tensor = 3; m = j / 3; g0 = (j - m * 3) * 4; }
  else { int j = job - 2400; tensor = 4; m = j / 3; g0 = (j - m * 3) * 4; }

  const float* src;
  int nch;
  bool feat;
  if (tensor == 0) { src = OF + (size_t)m * CF * NPIX; nch = CF; feat = true; }
  else if (tensor == 1) { src = DAF + (size_t)m * CF * NPIX; nch = CF; feat = true; }
  else if (tensor == 2) { src = OFP + (size_t)m * CF * NPIX; nch = CF; feat = true; }
  else if (tensor == 3) { src = OC + (size_t)m * CCODE * NPIX; nch = CCODE; feat = false; }
  else { src = OCP + (size_t)m * CCODE * NPIX; nch = CCODE; feat = false; }

  // ---- coordset list (thread 0; first barrier below publishes it) ----
  if (tid == 0) {
    int cnt = 0;
    if (tensor == 0) {
      sh_slot[0] = 1; sh_n[0] = m; sh_cb[0] = 0; cnt = 1;
      for (int i = 0; i < 5; ++i)
        for (int k = 0; k < NB; ++k)
          if (PERMS[i * NB + k] == m) {
            sh_slot[cnt] = 3 + i; sh_n[cnt] = k; sh_cb[cnt] = 1; ++cnt;
          }
    } else if (tensor == 1) { sh_slot[0] = 0; sh_n[0] = m; sh_cb[0] = 0; cnt = 1; }
    else if (tensor == 2) { sh_slot[0] = 2; sh_n[0] = m; sh_cb[0] = 1; cnt = 1; }
    else if (tensor == 3) {
      sh_slot[0] = 0; sh_n[0] = m; sh_cb[0] = 0; cnt = 1;
      for (int i = 0; i < 5; ++i)
        for (int k = 0; k < NB; ++k)
          if (PERMS[i * NB + k] == m) {
            sh_slot[cnt] = 2 + i; sh_n[cnt] = k; sh_cb[cnt] = 1; ++cnt;
          }
    } else { sh_slot[0] = 1; sh_n[0] = m; sh_cb[0] = 1; cnt = 1; }
    sh_ncs = cnt;
  }

  // ---- register-staged octet loader (static indices; 7x float4 = 28 VGPR) ----
  float4 buf0, buf1, buf2, buf3, buf4, buf5, buf6;
#define LOAD_OCT(OCT)                                                        \
  {                                                                          \
    const int c0_ = (OCT) * 8;                                               \
    int valid_ = nch - c0_;                                                  \
    valid_ = valid_ > 8 ? 8 : (valid_ < 0 ? 0 : valid_);                     \
    const int lim4_ = valid_ * (NPIX / 4);                                   \
    const float4* sc_ = (const float4*)(src + (size_t)c0_ * NPIX);           \
    int e_;                                                                  \
    e_ = tid;          buf0 = (e_ < lim4_) ? sc_[e_] : make_float4(0,0,0,0); \
    e_ = tid + 256;    buf1 = (e_ < lim4_) ? sc_[e_] : make_float4(0,0,0,0); \
    e_ = tid + 512;    buf2 = (e_ < lim4_) ? sc_[e_] : make_float4(0,0,0,0); \
    e_ = tid + 768;    buf3 = (e_ < lim4_) ? sc_[e_] : make_float4(0,0,0,0); \
    e_ = tid + 1024;   buf4 = (e_ < lim4_) ? sc_[e_] : make_float4(0,0,0,0); \
    e_ = tid + 1280;   buf5 = (e_ < lim4_) ? sc_[e_] : make_float4(0,0,0,0); \
    e_ = tid + 1536;                                                         \
    buf6 = (e_ < 1568 && e_ < lim4_) ? sc_[e_] : make_float4(0,0,0,0);       \
  }

  LOAD_OCT(g0);

  for (int g = 0; g < GOCT; ++g) {
    const int o = g0 + g;
    __syncthreads();  // prev sampling done (g=0: publishes sh_* list)
    {
      float4* pl4 = (float4*)planes;
      int e;
      e = tid;        pl4[e] = buf0;
      e = tid + 256;  pl4[e] = buf1;
      e = tid + 512;  pl4[e] = buf2;
      e = tid + 768;  pl4[e] = buf3;
      e = tid + 1024; pl4[e] = buf4;
      e = tid + 1280; pl4[e] = buf5;
      e = tid + 1536; if (e < 1568) pl4[e] = buf6;
    }
    __syncthreads();  // LDS ready
    if (g + 1 < GOCT) LOAD_OCT(g0 + g + 1);  // prefetch: latency hides under sampling

    // ---- sample octet o from LDS, pack bf16, write frags ----
    const int kp = o >> 2, lg = o & 3;
    const int total = sh_ncs * 128;
    for (int s = tid; s < total; s += 256) {
      const int cs = s >> 7, pt = s & 127;
      const int slot = sh_slot[cs], n = sh_n[cs];
      const float* cb = sh_cb[cs] ? CO2 : CO1;
      float v[8];
      if (pt < P) {
        int gi = pt / 11, gj = pt - gi * 11;
        int2 o2;
        float4 w4;
        mkcoord2(cb + (((n * 11 + gj) * 11 + gi) << 1), &o2, &w4);
#pragma unroll
        for (int i = 0; i < 8; ++i) {
          const float* pl = planes + i * NPIX;
          v[i] = w4.x * pl[o2.x] + w4.y * pl[o2.x + 1] + w4.z * pl[o2.y] +
                 w4.w * pl[o2.y + 1];
        }
      } else {
#pragma unroll
        for (int i = 0; i < 8; ++i) v[i] = 0.f;
      }
      uint4 q;
      q.x = (uint_t)f2bf(v[0]) | ((uint_t)f2bf(v[1]) << 16);
      q.y = (uint_t)f2bf(v[2]) | ((uint_t)f2bf(v[3]) << 16);
      q.z = (uint_t)f2bf(v[4]) | ((uint_t)f2bf(v[5]) << 16);
      q.w = (uint_t)f2bf(v[6]) | ((uint_t)f2bf(v[7]) << 16);
      size_t fragbase = feat ? (size_t)(slot * 32 + n) * FEAT_FRAG_SHORTS
                             : CODE_BASE_SHORTS + (size_t)(slot * 32 + n) * CODE_FRAG_SHORTS;
      *(uint4*)(frags + fragbase +
                ((size_t)((kp * 8 + (pt >> 4)) * 64 + lg * 16 + (pt & 15)) << 3)) = q;
    }
  }
#undef LOAD_OCT
}

// ===================== norms from bf16 frags =====================
// blocks 0..255: feat (slot=b>>5, n=b&31); 256..479: code.
__global__ __launch_bounds__(128) void norms_kernel(float* __restrict__ ws) {
  const ushort_t* frags = (const ushort_t*)(ws + WS_FRAG_FLOAT);
  const int b = blockIdx.x, p = threadIdx.x;
  float s = 0.f;
  if (b < 256) {
    const int slot = b >> 5, n = b & 31;
    const uint4* F = (const uint4*)(frags + (size_t)(slot * 32 + n) * FEAT_FRAG_SHORTS);
    for (int kp = 0; kp < 24; ++kp) {
#pragma unroll
      for (int lg = 0; lg < 4; ++lg) {
        uint4 q = F[(kp * 8 + (p >> 4)) * 64 + lg * 16 + (p & 15)];
        float a;
        a = bflo(q.x); s = fmaf(a, a, s); a = bfhi(q.x); s = fmaf(a, a, s);
        a = bflo(q.y); s = fmaf(a, a, s); a = bfhi(q.y); s = fmaf(a, a, s);
        a = bflo(q.z); s = fmaf(a, a, s); a = bfhi(q.z); s = fmaf(a, a, s);
        a = bflo(q.w); s = fmaf(a, a, s); a = bfhi(q.w); s = fmaf(a, a, s);
      }
    }
    ws[WS_INVF + (slot * 32 + n) * 128 + p] = 1.f / fmaxf(sqrtf(s), 1e-10f);
  } else {
    const int b2 = b - 256;
    const int slot = b2 >> 5, n = b2 & 31;
    const uint4* F = (const uint4*)(frags + CODE_BASE_SHORTS +
                                    (size_t)(slot * 32 + n) * CODE_FRAG_SHORTS);
#pragma unroll
    for (int kp = 0; kp < 3; ++kp) {
#pragma unroll
      for (int lg = 0; lg < 4; ++lg) {
        uint4 q = F[(kp * 8 + (p >> 4)) * 64 + lg * 16 + (p & 15)];
        float a;
        a = bflo(q.x); s = fmaf(a, a, s); a = bfhi(q.x); s = fmaf(a, a, s);
        a = bflo(q.y); s = fmaf(a, a, s); a = bfhi(q.y); s = fmaf(a, a, s);
        a = bflo(q.z); s = fmaf(a, a, s); a = bfhi(q.z); s = fmaf(a, a, s);
        a = bflo(q.w); s = fmaf(a, a, s); a = bfhi(q.w); s = fmaf(a, a, s);
      }
    }
    ws[WS_INVC + (slot * 32 + n) * 128 + p] = 1.f / fmaxf(sqrtf(s), 1e-10f);
  }
}

// ===================== MFMA Gram =====================
__global__ __launch_bounds__(256) void gram_mfma(float* __restrict__ ws,
                                                 float* __restrict__ out) {
  const ushort_t* frags = (const ushort_t*)(ws + WS_FRAG_FLOAT);
  const int bid = blockIdx.x, pair = bid >> 5, n = bid & 31;
  const int tid = threadIdx.x, wave = tid >> 6, lane = tid & 63;
  __shared__ float invAf[128], invBf[128], invAc[128], invBc[128];
  __shared__ float red[4][3];
  const int afslot = (pair == 0) ? 0 : 1;
  const int bfslot = (pair == 0) ? 0 : (pair == 1 ? 2 : 3 + (pair - 2));
  const int bcslot = (pair == 0) ? 0 : (pair == 1 ? 1 : 2 + (pair - 2));
  if (tid < 128) {
    invAf[tid] = ws[WS_INVF + (afslot * 32 + n) * 128 + tid];
    invBf[tid] = ws[WS_INVF + (bfslot * 32 + n) * 128 + tid];
    invAc[tid] = ws[WS_INVC + (0 * 32 + n) * 128 + tid];
    invBc[tid] = ws[WS_INVC + (bcslot * 32 + n) * 128 + tid];
  }
  __syncthreads();

  const short8* Af = (const short8*)(frags + (size_t)(afslot * 32 + n) * FEAT_FRAG_SHORTS);
  const short8* Bf = (const short8*)(frags + (size_t)(bfslot * 32 + n) * FEAT_FRAG_SHORTS);

  f32x4 acc[2][8];
#pragma unroll
  for (int j = 0; j < 2; ++j)
#pragma unroll
    for (int t = 0; t < 8; ++t) acc[j][t] = (f32x4){0.f, 0.f, 0.f, 0.f};

#pragma unroll 2
  for (int kp = 0; kp < 24; ++kp) {
    short8 a0 = Af[(kp * 8 + 2 * wave) * 64 + lane];
    short8 a1 = Af[(kp * 8 + 2 * wave + 1) * 64 + lane];
    short8 bv[8];
#pragma unroll
    for (int t = 0; t < 8; ++t) bv[t] = Bf[(kp * 8 + t) * 64 + lane];
#pragma unroll
    for (int t = 0; t < 8; ++t) {
      acc[0][t] = __builtin_amdgcn_mfma_f32_16x16x32_bf16(a0, bv[t], acc[0][t], 0, 0, 0);
      acc[1][t] = __builtin_amdgcn_mfma_f32_16x16x32_bf16(a1, bv[t], acc[1][t], 0, 0, 0);
    }
  }

  // ---- feats epilogue: normalize, row-center (fd kept in acc) ----
  const int lane4 = (lane >> 4) << 2;
  const int cl15 = lane & 15;
  float sfd = 0.f;
#pragma unroll
  for (int j = 0; j < 2; ++j) {
    const int rb = (2 * wave + j) * 16 + lane4;
    const float ivr0 = invAf[rb], ivr1 = invAf[rb + 1], ivr2 = invAf[rb + 2],
                ivr3 = invAf[rb + 3];
    float rs0 = 0.f, rs1 = 0.f, rs2 = 0.f, rs3 = 0.f;
#pragma unroll
    for (int t = 0; t < 8; ++t) {
      const float ivc = invBf[t * 16 + cl15];
      float v0 = acc[j][t].x * ivr0 * ivc;
      float v1 = acc[j][t].y * ivr1 * ivc;
      float v2 = acc[j][t].z * ivr2 * ivc;
      float v3 = acc[j][t].w * ivr3 * ivc;
      acc[j][t].x = v0; acc[j][t].y = v1; acc[j][t].z = v2; acc[j][t].w = v3;
      rs0 += v0; rs1 += v1; rs2 += v2; rs3 += v3;
    }
    sfd += rs0 + rs1 + rs2 + rs3;
    rs0 += __shfl_xor(rs0, 1); rs0 += __shfl_xor(rs0, 2);
    rs0 += __shfl_xor(rs0, 4); rs0 += __shfl_xor(rs0, 8);
    rs1 += __shfl_xor(rs1, 1); rs1 += __shfl_xor(rs1, 2);
    rs1 += __shfl_xor(rs1, 4); rs1 += __shfl_xor(rs1, 8);
    rs2 += __shfl_xor(rs2, 1); rs2 += __shfl_xor(rs2, 2);
    rs2 += __shfl_xor(rs2, 4); rs2 += __shfl_xor(rs2, 8);
    rs3 += __shfl_xor(rs3, 1); rs3 += __shfl_xor(rs3, 2);
    rs3 += __shfl_xor(rs3, 4); rs3 += __shfl_xor(rs3, 8);
    const float rm0 = rs0 * (1.f / 121.f), rm1 = rs1 * (1.f / 121.f);
    const float rm2 = rs2 * (1.f / 121.f), rm3 = rs3 * (1.f / 121.f);
#pragma unroll
    for (int t = 0; t < 8; ++t) {
      acc[j][t].x -= rm0; acc[j][t].y -= rm1; acc[j][t].z -= rm2; acc[j][t].w -= rm3;
    }
  }

  int cd_base, loss_base = 0;
  if (pair == 0) cd_base = OFF_PI_CD + n * 14641;
  else if (pair == 1) cd_base = OFF_PO_CD + n * 14641;
  else {
    int t0 = ((pair - 2) * NB + n) * 14641;
    cd_base = OFF_NEG_CD + t0;
    loss_base = OFF_NEG_LOSS + t0;
  }

  if (pair >= 2) {
#pragma unroll
    for (int j = 0; j < 2; ++j) {
      const int rb = (2 * wave + j) * 16 + lane4;
      if (rb < P) {
#pragma unroll
        for (int t = 0; t < 8; ++t) {
          const int c = t * 16 + cl15;
          if (c < P) {
            float* o = out + loss_base + rb * P + c;
            o[0] = acc[j][t].x;
            if (rb + 1 < P) o[P] = acc[j][t].y;
            if (rb + 2 < P) o[2 * P] = acc[j][t].z;
            if (rb + 3 < P) o[3 * P] = acc[j][t].w;
          }
        }
      }
    }
  }

  // ---- code Gram ----
  const short8* Ac = (const short8*)(frags + CODE_BASE_SHORTS + (size_t)n * CODE_FRAG_SHORTS);
  const short8* Bc = (const short8*)(frags + CODE_BASE_SHORTS + (size_t)(bcslot * 32 + n) * CODE_FRAG_SHORTS);
  f32x4 cacc[2][8];
#pragma unroll
  for (int j = 0; j < 2; ++j)
#pragma unroll
    for (int t = 0; t < 8; ++t) cacc[j][t] = (f32x4){0.f, 0.f, 0.f, 0.f};
#pragma unroll
  for (int kp = 0; kp < 3; ++kp) {
    short8 a0 = Ac[(kp * 8 + 2 * wave) * 64 + lane];
    short8 a1 = Ac[(kp * 8 + 2 * wave + 1) * 64 + lane];
    short8 bv[8];
#pragma unroll
    for (int t = 0; t < 8; ++t) bv[t] = Bc[(kp * 8 + t) * 64 + lane];
#pragma unroll
    for (int t = 0; t < 8; ++t) {
      cacc[0][t] = __builtin_amdgcn_mfma_f32_16x16x32_bf16(a0, bv[t], cacc[0][t], 0, 0, 0);
      cacc[1][t] = __builtin_amdgcn_mfma_f32_16x16x32_bf16(a1, bv[t], cacc[1][t], 0, 0, 0);
    }
  }

  float s1 = 0.f, s2 = 0.f;
#pragma unroll
  for (int j = 0; j < 2; ++j) {
    const int rb = (2 * wave + j) * 16 + lane4;
    const float ivr0 = invAc[rb], ivr1 = invAc[rb + 1], ivr2 = invAc[rb + 2],
                ivr3 = invAc[rb + 3];
#pragma unroll
    for (int t = 0; t < 8; ++t) {
      const int c = t * 16 + cl15;
      const float ivc = invBc[c];
      float c0v = cacc[j][t].x * ivr0 * ivc;
      float c1v = cacc[j][t].y * ivr1 * ivc;
      float c2v = cacc[j][t].z * ivr2 * ivc;
      float c3v = cacc[j][t].w * ivr3 * ivc;
      if (c < P && rb < P) {
        float* o = out + cd_base + rb * P + c;
        o[0] = c0v;
        if (rb + 1 < P) o[P] = c1v;
        if (rb + 2 < P) o[2 * P] = c2v;
        if (rb + 3 < P) o[3 * P] = c3v;
      }
      if (pair < 2) {
        float cl0 = fminf(fmaxf(c0v, 0.f), 0.8f);
        float cl1 = fminf(fmaxf(c1v, 0.f), 0.8f);
        float cl2 = fminf(fmaxf(c2v, 0.f), 0.8f);
        float cl3 = fminf(fmaxf(c3v, 0.f), 0.8f);
        s1 = fmaf(cl0, acc[j][t].x, s1);
        s1 = fmaf(cl1, acc[j][t].y, s1);
        s1 = fmaf(cl2, acc[j][t].z, s1);
        s1 = fmaf(cl3, acc[j][t].w, s1);
        s2 += cl0 + cl1 + cl2 + cl3;
      }
    }
  }

#pragma unroll
  for (int m = 1; m < 64; m <<= 1) {
    sfd += __shfl_xor(sfd, m);
    s1 += __shfl_xor(s1, m);
    s2 += __shfl_xor(s2, m);
  }
  if ((tid & 63) == 0) { red[wave][0] = sfd; red[wave][1] = s1; red[wave][2] = s2; }
  __syncthreads();
  if (tid == 0) {
    float a = 0.f, b2 = 0.f, c2 = 0.f;
    for (int w = 0; w < 4; ++w) { a += red[w][0]; b2 += red[w][1]; c2 += red[w][2]; }
    float* bsums = ws + WS_BSUMS;
    bsums[bid * 3 + 0] = a;
    bsums[bid * 3 + 1] = b2;
    bsums[bid * 3 + 2] = c2;
  }
}

__global__ void loss_finish2(float* __restrict__ ws, float* __restrict__ out) {
  __shared__ float s[7][3];
  const float* bsums = ws + WS_BSUMS;
  float* addterm = ws + WS_ADDT;
  int tid = threadIdx.x;
  if (tid < 21) {
    int pr = tid / 3, k = tid % 3;
    float a = 0.f;
    for (int i = 0; i < 32; ++i) a += bsums[(pr * 32 + i) * 3 + k];
    s[pr][k] = a;
  }
  __syncthreads();
  if (tid == 0) {
    const float invN = 1.f / NTOTF;
    out[OFF_PI_SCALAR] = -(s[0][1] + (s[0][0] * invN - 0.18f) * s[0][2]) * invN;
    out[OFF_PO_SCALAR] = -(s[1][1] + (s[1][0] * invN - 0.12f) * s[1][2]) * invN;
  }
  if (tid >= 1 && tid < 6) addterm[tid - 1] = s[tid + 1][0] / NTOTF - 0.46f;
}

__global__ __launch_bounds__(256) void neg_loss_kernel(
    float* __restrict__ lossr, const float* __restrict__ cdr,
    const float* __restrict__ addterm) {
  __shared__ float at[5];
  if (threadIdx.x < 5) at[threadIdx.x] = addterm[threadIdx.x];
  __syncthreads();
  const int total4 = 5 * 117128;  // 468512/4 per pair
  float4* l4 = (float4*)lossr;
  const float4* c4 = (const float4*)cdr;
  for (int e = blockIdx.x * 256 + threadIdx.x; e < total4; e += gridDim.x * 256) {
    int k = e / 117128;
    float4 cd = c4[e];
    float4 fv = l4[e];
    float a = at[k];
    float4 r;
    r.x = -fminf(fmaxf(cd.x, 0.f), 0.8f) * (fv.x + a);
    r.y = -fminf(fmaxf(cd.y, 0.f), 0.8f) * (fv.y + a);
    r.z = -fminf(fmaxf(cd.z, 0.f), 0.8f) * (fv.z + a);
    r.w = -fminf(fmaxf(cd.w, 0.f), 0.8f) * (fv.w + a);
    l4[e] = r;
  }
}

// ===================== fallback path (round-1, verified) =====================

__global__ __launch_bounds__(256) void loss_main_fb(
    const float* __restrict__ OF, const float* __restrict__ OFP,
    const float* __restrict__ OC, const float* __restrict__ OCP,
    const float* __restrict__ DAF,
    const float* __restrict__ CO1, const float* __restrict__ CO2,
    const int* __restrict__ PERMS,
    float* __restrict__ out, float* __restrict__ bsums) {
  const int b = blockIdx.x;
  const int pair = b >> 7;
  const int rem = b & 127;
  const int n = rem >> 2;
  const int rg = rem & 3;
  const int row_start = rg * 31;
  const int rcount = min(31, P - row_start);
  const int tid = threadIdx.x;
  const int tx = tid & 15, ty = tid >> 4;

  const float *F1, *F2, *C1, *C2, *CB;
  if (pair == 0) {
    F1 = DAF + (size_t)n * CF * NPIX; F2 = F1;
    C1 = OC + (size_t)n * CCODE * NPIX; C2 = C1;
    CB = CO1;
  } else if (pair == 1) {
    F1 = OF + (size_t)n * CF * NPIX; F2 = OFP + (size_t)n * CF * NPIX;
    C1 = OC + (size_t)n * CCODE * NPIX; C2 = OCP + (size_t)n * CCODE * NPIX;
    CB = CO2;
  } else {
    int n2 = PERMS[(pair - 2) * NB + n];
    F1 = OF + (size_t)n * CF * NPIX; F2 = OF + (size_t)n2 * CF * NPIX;
    C1 = OC + (size_t)n * CCODE * NPIX; C2 = OC + (size_t)n2 * CCODE * NPIX;
    CB = CO2;
  }

  __shared__ int4 Bo[P];
  __shared__ float4 Bw[P];
  __shared__ int4 Ao[32];
  __shared__ float4 Aw[32];
  __shared__ float Abuf[CCODE][32];
  __shared__ float Bbuf[CCODE][128];
  __shared__ float invA[32], invB[128];
  __shared__ float red[4][3];

  if (tid < P) {
    int gi = tid / 11, gj = tid - gi * 11;
    const float* cp = CB + (((n * 11 + gj) * 11 + gi) << 1);
    mkcoord(cp, &Bo[tid], &Bw[tid]);
  } else if (tid >= 128 && tid < 160) {
    int r = tid - 128;
    int q = row_start + r;
    if (q < P) {
      int gi = q / 11, gj = q - gi * 11;
      const float* cp = CO1 + (((n * 11 + gj) * 11 + gi) << 1);
      mkcoord(cp, &Ao[r], &Aw[r]);
    }
  }
  __syncthreads();

  float acc[2][2][4];
#pragma unroll
  for (int kr = 0; kr < 2; ++kr)
#pragma unroll
    for (int m = 0; m < 2; ++m)
#pragma unroll
      for (int u = 0; u < 4; ++u) acc[kr][m][u] = 0.f;
  float ansq = 0.f, bnsq = 0.f;

  for (int ch = 0; ch < 12; ++ch) {
    const int c0 = ch * 64;
    if (ch) __syncthreads();
    for (int e = tid; e < 64 * 128; e += 256) {
      int col = e & 127, cc = e >> 7;
      float v = 0.f;
      if (col < P) v = samp4(F2, c0 + cc, Bo[col], Bw[col]);
      Bbuf[cc][col] = v;
    }
    for (int e = tid; e < 64 * 32; e += 256) {
      int col = e & 31, cc = e >> 5;
      float v = 0.f;
      if (col < rcount) v = samp4(F1, c0 + cc, Ao[col], Aw[col]);
      Abuf[cc][col] = v;
    }
    __syncthreads();
    if (tid < 128) {
      float s = 0.f;
      for (int cc = 0; cc < 64; ++cc) { float v = Bbuf[cc][tid]; s = fmaf(v, v, s); }
      bnsq += s;
    } else if (tid < 160) {
      int r = tid - 128;
      float s = 0.f;
      for (int cc = 0; cc < 64; ++cc) { float v = Abuf[cc][r]; s = fmaf(v, v, s); }
      ansq += s;
    }
    for (int cc = 0; cc < 64; ++cc) {
      const float2 av = *(const float2*)&Abuf[cc][ty * 2];
      const float4 b0 = *(const float4*)&Bbuf[cc][tx * 4];
      const float4 b1 = *(const float4*)&Bbuf[cc][tx * 4 + 64];
      float a[2] = {av.x, av.y};
      float bb[2][4] = {{b0.x, b0.y, b0.z, b0.w}, {b1.x, b1.y, b1.z, b1.w}};
#pragma unroll
      for (int kr = 0; kr < 2; ++kr)
#pragma unroll
        for (int m = 0; m < 2; ++m)
#pragma unroll
          for (int u = 0; u < 4; ++u)
            acc[kr][m][u] = fmaf(a[kr], bb[m][u], acc[kr][m][u]);
    }
  }
  __syncthreads();
  if (tid < 128) invB[tid] = (tid < P) ? 1.f / fmaxf(sqrtf(bnsq), 1e-10f) : 0.f;
  else if (tid < 160) {
    int r = tid - 128;
    invA[r] = (r < rcount) ? 1.f / fmaxf(sqrtf(ansq), 1e-10f) : 0.f;
  }
  __syncthreads();

  float ia[2] = {invA[2 * ty], invA[2 * ty + 1]};
  float ib[2][4];
#pragma unroll
  for (int m = 0; m < 2; ++m)
#pragma unroll
    for (int u = 0; u < 4; ++u) ib[m][u] = invB[m * 64 + tx * 4 + u];

  float fdc[2][2][4];
  float sfd = 0.f;
#pragma unroll
  for (int kr = 0; kr < 2; ++kr) {
    float part = 0.f;
#pragma unroll
    for (int m = 0; m < 2; ++m)
#pragma unroll
      for (int u = 0; u < 4; ++u) {
        float v = acc[kr][m][u] * ia[kr] * ib[m][u];
        fdc[kr][m][u] = v;
        part += v;
      }
    sfd += part;
    float rs = part;
#pragma unroll
    for (int s = 1; s < 16; s <<= 1) rs += __shfl_xor(rs, s, 16);
    float rowm = rs * (1.f / 121.f);
#pragma unroll
    for (int m = 0; m < 2; ++m)
#pragma unroll
      for (int u = 0; u < 4; ++u) fdc[kr][m][u] -= rowm;
  }
  __syncthreads();

  for (int e = tid; e < CCODE * 128; e += 256) {
    int col = e & 127, cc = e >> 7;
    float v = 0.f;
    if (col < P) v = samp4(C2, cc, Bo[col], Bw[col]);
    Bbuf[cc][col] = v;
  }
  for (int e = tid; e < CCODE * 32; e += 256) {
    int col = e & 31, cc = e >> 5;
    float v = 0.f;
    if (col < rcount) v = samp4(C1, cc, Ao[col], Aw[col]);
    Abuf[cc][col] = v;
  }
  __syncthreads();
  if (tid < 128) {
    float s = 0.f;
    for (int cc = 0; cc < CCODE; ++cc) { float v = Bbuf[cc][tid]; s = fmaf(v, v, s); }
    invB[tid] = (tid < P) ? 1.f / fmaxf(sqrtf(s), 1e-10f) : 0.f;
  } else if (tid < 160) {
    int r = tid - 128;
    float s = 0.f;
    for (int cc = 0; cc < CCODE; ++cc) { float v = Abuf[cc][r]; s = fmaf(v, v, s); }
    invA[r] = (r < rcount) ? 1.f / fmaxf(sqrtf(s), 1e-10f) : 0.f;
  }
  float cacc[2][2][4];
#pragma unroll
  for (int kr = 0; kr < 2; ++kr)
#pragma unroll
    for (int m = 0; m < 2; ++m)
#pragma unroll
      for (int u = 0; u < 4; ++u) cacc[kr][m][u] = 0.f;
  for (int cc = 0; cc < CCODE; ++cc) {
    const float2 av = *(const float2*)&Abuf[cc][ty * 2];
    const float4 b0 = *(const float4*)&Bbuf[cc][tx * 4];
    const float4 b1 = *(const float4*)&Bbuf[cc][tx * 4 + 64];
    float a[2] = {av.x, av.y};
    float bb[2][4] = {{b0.x, b0.y, b0.z, b0.w}, {b1.x, b1.y, b1.z, b1.w}};
#pragma unroll
    for (int kr = 0; kr < 2; ++kr)
#pragma unroll
      for (int m = 0; m < 2; ++m)
#pragma unroll
        for (int u = 0; u < 4; ++u)
          cacc[kr][m][u] = fmaf(a[kr], bb[m][u], cacc[kr][m][u]);
  }
  __syncthreads();
  float iac[2] = {invA[2 * ty], invA[2 * ty + 1]};
  float ibc[2][4];
#pragma unroll
  for (int m = 0; m < 2; ++m)
#pragma unroll
    for (int u = 0; u < 4; ++u) ibc[m][u] = invB[m * 64 + tx * 4 + u];

  int cd_base, loss_base = 0;
  if (pair == 0) cd_base = OFF_PI_CD + n * 14641;
  else if (pair == 1) cd_base = OFF_PO_CD + n * 14641;
  else {
    int t = ((pair - 2) * NB + n) * 14641;
    cd_base = OFF_NEG_CD + t;
    loss_base = OFF_NEG_LOSS + t;
  }

  float s1 = 0.f, s2 = 0.f;
#pragma unroll
  for (int kr = 0; kr < 2; ++kr) {
    int r = 2 * ty + kr;
    if (r < rcount) {
      int rglob = row_start + r;
#pragma unroll
      for (int m = 0; m < 2; ++m)
#pragma unroll
        for (int u = 0; u < 4; ++u) {
          int c = m * 64 + tx * 4 + u;
          if (c < P) {
            float cdv = cacc[kr][m][u] * iac[kr] * ibc[m][u];
            int idx = rglob * P + c;
            out[cd_base + idx] = cdv;
            float cl = fminf(fmaxf(cdv, 0.f), 0.8f);
            float fv = fdc[kr][m][u];
            if (pair < 2) { s1 = fmaf(cl, fv, s1); s2 += cl; }
            else out[loss_base + idx] = fv;
          }
        }
    }
  }

#pragma unroll
  for (int s = 1; s < 64; s <<= 1) {
    sfd += __shfl_xor(sfd, s);
    s1 += __shfl_xor(s1, s);
    s2 += __shfl_xor(s2, s);
  }
  int wv = tid >> 6;
  if ((tid & 63) == 0) { red[wv][0] = sfd; red[wv][1] = s1; red[wv][2] = s2; }
  __syncthreads();
  if (tid == 0) {
    float a = 0.f, bb = 0.f, cc = 0.f;
    for (int w = 0; w < 4; ++w) { a += red[w][0]; bb += red[w][1]; cc += red[w][2]; }
    bsums[b * 3 + 0] = a;
    bsums[b * 3 + 1] = bb;
    bsums[b * 3 + 2] = cc;
  }
}

__global__ void loss_finish_fb(const float* __restrict__ bsums,
                               float* __restrict__ out,
                               float* __restrict__ addterm) {
  __shared__ float s[7][3];
  int tid = threadIdx.x;
  if (tid < 21) {
    int pr = tid / 3, k = tid % 3;
    float a = 0.f;
    const float* p = bsums + (pr * 128) * 3 + k;
    for (int i = 0; i < 128; ++i) a += p[i * 3];
    s[pr][k] = a;
  }
  __syncthreads();
  if (tid == 0) {
    const float invN = 1.f / NTOTF;
    out[OFF_PI_SCALAR] = -(s[0][1] + (s[0][0] * invN - 0.18f) * s[0][2]) * invN;
    out[OFF_PO_SCALAR] = -(s[1][1] + (s[1][0] * invN - 0.12f) * s[1][2]) * invN;
  }
  if (tid >= 1 && tid < 6) addterm[tid - 1] = s[tid + 1][0] / NTOTF - 0.46f;
}

__global__ __launch_bounds__(256) void neg_loss_fb(
    float* __restrict__ lossr, const float* __restrict__ cdr,
    const float* __restrict__ addterm) {
  __shared__ float at[5];
  if (threadIdx.x < 5) at[threadIdx.x] = addterm[threadIdx.x];
  __syncthreads();
  const int total = 5 * 468512;
  for (int e = blockIdx.x * 256 + threadIdx.x; e < total; e += gridDim.x * 256) {
    int k = e / 468512;
    float cdv = cdr[e];
    float cl = fminf(fmaxf(cdv, 0.f), 0.8f);
    lossr[e] = -cl * (lossr[e] + at[k]);
  }
}

extern "C" void kernel_launch(void* const* d_in, const int* in_sizes, int n_in,
                              void* d_out, int out_size, void* d_ws,
                              size_t ws_size, hipStream_t stream) {
  const float* OF = (const float*)d_in[0];
  const float* OFP = (const float*)d_in[1];
  const float* OC = (const float*)d_in[4];
  const float* OCP = (const float*)d_in[5];
  const float* DAF = (const float*)d_in[6];
  const float* CO1 = (const float*)d_in[8];
  const float* CO2 = (const float*)d_in[9];
  const int* PERMS = (const int*)d_in[10];
  float* out = (float*)d_out;
  float* ws = (float*)d_ws;

  if (ws_size >= (size_t)WS_NEED2 * sizeof(float)) {
    hipLaunchKernelGGL(presample_pipe, dim3(2496), dim3(256), 0, stream,
                       OF, OFP, OC, OCP, DAF, CO1, CO2, PERMS, ws);
    hipLaunchKernelGGL(norms_kernel, dim3(480), dim3(128), 0, stream, ws);
    hipLaunchKernelGGL(gram_mfma, dim3(224), dim3(256), 0, stream, ws, out);
    hipLaunchKernelGGL(loss_finish2, dim3(1), dim3(64), 0, stream, ws, out);
    hipLaunchKernelGGL(neg_loss_kernel, dim3(1024), dim3(256), 0, stream,
                       out + OFF_NEG_LOSS, out + OFF_NEG_CD, ws + WS_ADDT);
  } else {
    float* bsums = ws;
    float* addterm = bsums + 896 * 3;
    hipLaunchKernelGGL(loss_main_fb, dim3(896), dim3(256), 0, stream,
                       OF, OFP, OC, OCP, DAF, CO1, CO2, PERMS, out, bsums);
    hipLaunchKernelGGL(loss_finish_fb, dim3(1), dim3(64), 0, stream,
                       bsums, out, addterm);
    hipLaunchKernelGGL(neg_loss_fb, dim3(2048), dim3(256), 0, stream,
                       out + OFF_NEG_LOSS, out + OFF_NEG_CD, addterm);
  }
}